// Round 1
// baseline (14432.968 us; speedup 1.0000x reference)
//
#include <hip/hip_runtime.h>
#include <math.h>

#define S_ANCH 1024
#define B_QRY  2048
#define N_TOT  3072
#define D_DIM  1352
#define F_NUM  10
#define N_TV   19

static const size_t ND = (size_t)N_TOT * D_DIM;         // 4,153,344
static const size_t SD = (size_t)S_ANCH * D_DIM;        // 1,384,448
static const size_t NS = (size_t)N_TOT * S_ANCH;        // 3,145,728
static const size_t OUT_Z = (size_t)B_QRY * F_NUM * S_ANCH; // 20,971,520

struct W10 { float w[F_NUM]; };

// ---------------- init: zero z, cost, and the t=0 output slice ----------------
__global__ __launch_bounds__(256) void init_kernel(float* __restrict__ z,
                                                   float* __restrict__ cost,
                                                   float* __restrict__ out) {
    size_t idx = (size_t)blockIdx.x * blockDim.x + threadIdx.x;
    size_t stride = (size_t)gridDim.x * blockDim.x;
    for (size_t i = idx; i < NS; i += stride) z[i] = 0.f;
    const size_t NO = (size_t)B_QRY * S_ANCH;
    for (size_t i = idx; i < NO; i += stride) {
        size_t b = i >> 10, s = i & 1023;
        out[b * (size_t)(F_NUM * S_ANCH) + s] = 0.f;
    }
    if (idx == 0) cost[0] = 0.f;
}

// ---------------- c_t[s,d] = sum_f c_s[s,d,f] * w[f] ----------------
__global__ __launch_bounds__(256) void compute_c_kernel(const float* __restrict__ cs,
                                                        float* __restrict__ c, W10 W) {
    size_t idx = (size_t)blockIdx.x * 256 + threadIdx.x;
    if (idx >= SD) return;
    const float* p = cs + idx * F_NUM;
    float s = 0.f;
#pragma unroll
    for (int f = 0; f < F_NUM; f++) s += p[f] * W.w[f];
    c[idx] = s;
}

// ---------------- psi_t[n,d] : conv (stride2,valid,3x3) fused with freq dot ----------------
__global__ __launch_bounds__(256) void conv_psi_kernel(const float* __restrict__ data,
                                                       const float* __restrict__ inputs,
                                                       const float* __restrict__ cw,
                                                       const float* __restrict__ cb,
                                                       float* __restrict__ psi, W10 W) {
    __shared__ float wsh[720];
    __shared__ float bsh[80];
    for (int i = threadIdx.x; i < 720; i += 256) wsh[i] = cw[i];
    for (int i = threadIdx.x; i < 80; i += 256) bsh[i] = cb[i];
    __syncthreads();
    size_t idx = (size_t)blockIdx.x * 256 + threadIdx.x;
    if (idx >= (size_t)N_TOT * 8 * 169) return;
    int pos = (int)(idx % 169);
    int rest = (int)(idx / 169);
    int c8 = rest & 7;
    int n = rest >> 3;
    int oi = pos / 13, oj = pos % 13;
    const float* x = (n < S_ANCH) ? (data + (size_t)n * 784)
                                  : (inputs + (size_t)(n - S_ANCH) * 784);
    float vin[9];
#pragma unroll
    for (int kh = 0; kh < 3; kh++)
#pragma unroll
        for (int kw = 0; kw < 3; kw++)
            vin[kh * 3 + kw] = x[(2 * oi + kh) * 28 + (2 * oj + kw)];
    float p = 0.f;
#pragma unroll
    for (int f = 0; f < F_NUM; f++) {
        int co = f * 8 + c8;
        float s = bsh[co];
#pragma unroll
        for (int t = 0; t < 9; t++) s += vin[t] * wsh[co * 9 + t];
        p += s * W.w[f];
    }
    psi[(size_t)n * D_DIM + c8 * 169 + pos] = p;
}

// ---------------- GEMM NN: C[m,n] = sum_k A[m,k]*B[k,n] (+ P[m,n]) ----------------
// A:[M,K] rm, B:[K,Nn] rm, C:[M,Nn] rm. M%64==0, K%16==0; Nn edge guarded.
__global__ __launch_bounds__(256) void gemm_nn_kernel(const float* __restrict__ A,
                                                      const float* __restrict__ B,
                                                      const float* __restrict__ P,
                                                      float* __restrict__ C,
                                                      int M, int Nn, int K) {
    __shared__ __align__(16) float As[16][68];
    __shared__ __align__(16) float Bs[16][64];
    int bm = blockIdx.y * 64, bn = blockIdx.x * 64;
    int tid = threadIdx.x;
    int tx = tid & 15, ty = tid >> 4;
    float acc[4][4] = {};
    for (int k0 = 0; k0 < K; k0 += 16) {
#pragma unroll
        for (int i = 0; i < 4; i++) {
            int idx = tid + i * 256;
            int r = idx >> 4, c = idx & 15;
            As[c][r] = A[(size_t)(bm + r) * K + k0 + c];
        }
#pragma unroll
        for (int i = 0; i < 4; i++) {
            int idx = tid + i * 256;
            int r = idx >> 6, c = idx & 63;
            int nc = bn + c;
            Bs[r][c] = (nc < Nn) ? B[(size_t)(k0 + r) * Nn + nc] : 0.f;
        }
        __syncthreads();
#pragma unroll
        for (int k = 0; k < 16; k++) {
            float4 av = *(const float4*)&As[k][ty * 4];
            float4 bv = *(const float4*)&Bs[k][tx * 4];
            float a4[4] = {av.x, av.y, av.z, av.w};
            float b4[4] = {bv.x, bv.y, bv.z, bv.w};
#pragma unroll
            for (int i = 0; i < 4; i++)
#pragma unroll
                for (int j = 0; j < 4; j++) acc[i][j] += a4[i] * b4[j];
        }
        __syncthreads();
    }
#pragma unroll
    for (int i = 0; i < 4; i++) {
        int m = bm + ty * 4 + i;
#pragma unroll
        for (int j = 0; j < 4; j++) {
            int nc = bn + tx * 4 + j;
            if (nc < Nn) {
                float v = acc[i][j];
                if (P) v += P[(size_t)m * Nn + nc];
                C[(size_t)m * Nn + nc] = v;
            }
        }
    }
}

// ---------------- GEMM NT + kernel epilogue ----------------
// C[m,s] = f( sum_k A[m,k]*Bm[s,k] ), A:[M,K] rm, Bm:[Nn,K] rm. K edge guarded.
// epilogue: uv = g*scale[m]*scale[s]; out = exp(uv - a[m] - a[s]) * uv
__global__ __launch_bounds__(256) void gemm_nt_kernel(const float* __restrict__ A,
                                                      const float* __restrict__ Bm,
                                                      const float* __restrict__ scl,
                                                      const float* __restrict__ ah,
                                                      float* __restrict__ C,
                                                      int M, int Nn, int K) {
    __shared__ __align__(16) float As[16][68];
    __shared__ __align__(16) float Bs[16][68];
    int bm = blockIdx.y * 64, bn = blockIdx.x * 64;
    int tid = threadIdx.x;
    int tx = tid & 15, ty = tid >> 4;
    float acc[4][4] = {};
    for (int k0 = 0; k0 < K; k0 += 16) {
#pragma unroll
        for (int i = 0; i < 4; i++) {
            int idx = tid + i * 256;
            int r = idx >> 4, c = idx & 15;
            int kk = k0 + c;
            As[c][r] = (kk < K) ? A[(size_t)(bm + r) * K + kk] : 0.f;
            Bs[c][r] = (kk < K) ? Bm[(size_t)(bn + r) * K + kk] : 0.f;
        }
        __syncthreads();
#pragma unroll
        for (int k = 0; k < 16; k++) {
            float4 av = *(const float4*)&As[k][ty * 4];
            float4 bv = *(const float4*)&Bs[k][tx * 4];
            float a4[4] = {av.x, av.y, av.z, av.w};
            float b4[4] = {bv.x, bv.y, bv.z, bv.w};
#pragma unroll
            for (int i = 0; i < 4; i++)
#pragma unroll
                for (int j = 0; j < 4; j++) acc[i][j] += a4[i] * b4[j];
        }
        __syncthreads();
    }
#pragma unroll
    for (int i = 0; i < 4; i++) {
        int m = bm + ty * 4 + i;
        float sm = scl[m], am = ah[m];
#pragma unroll
        for (int j = 0; j < 4; j++) {
            int s = bn + tx * 4 + j;
            float uv = acc[i][j] * sm * scl[s];
            float v = expf(uv - am - ah[s]) * uv;
            C[(size_t)m * Nn + s] = v;
        }
    }
}

// ---------------- per-row squash stats: scale[n], a[n] ----------------
__global__ __launch_bounds__(256) void rowstats_kernel(const float* __restrict__ u,
                                                       float* __restrict__ scl,
                                                       float* __restrict__ ah) {
    int n = blockIdx.x;
    const float* row = u + (size_t)n * D_DIM;
    float s = 0.f;
    for (int d = threadIdx.x; d < D_DIM; d += 256) {
        float v = row[d];
        s += v * v;
    }
    for (int o = 32; o > 0; o >>= 1) s += __shfl_down(s, o);
    __shared__ float red[4];
    if ((threadIdx.x & 63) == 0) red[threadIdx.x >> 6] = s;
    __syncthreads();
    if (threadIdx.x == 0) {
        float tot = red[0] + red[1] + red[2] + red[3];
        float norm = sqrtf(tot + 1e-6f);
        float sg = 1.f / (1.f + expf(-norm));
        float sc = sg / norm;
        scl[n] = sc;
        ah[n] = 0.5f * tot * sc * sc;
    }
}

// ---------------- RK4 bookkeeping ----------------
__global__ __launch_bounds__(256) void combine_kernel(float* __restrict__ accb,
                                                      float* __restrict__ ztmp,
                                                      const float* __restrict__ zcur,
                                                      const float* __restrict__ kcur,
                                                      float coef, float alpha, int first) {
    size_t idx = (size_t)blockIdx.x * blockDim.x + threadIdx.x;
    size_t stride = (size_t)gridDim.x * blockDim.x;
    for (size_t i = idx; i < NS; i += stride) {
        float k = kcur[i];
        if (first) accb[i] = k;
        else accb[i] += coef * k;
        ztmp[i] = zcur[i] + alpha * k;
    }
}

__global__ __launch_bounds__(256) void finish_kernel(float* __restrict__ zcur,
                                                     const float* __restrict__ accb,
                                                     const float* __restrict__ kcur,
                                                     float h6, float* __restrict__ out,
                                                     int tout) {
    size_t idx = (size_t)blockIdx.x * blockDim.x + threadIdx.x;
    size_t stride = (size_t)gridDim.x * blockDim.x;
    for (size_t i = idx; i < NS; i += stride) {
        float z = zcur[i] + h6 * (accb[i] + kcur[i]);
        zcur[i] = z;
        size_t n = i >> 10, s = i & 1023;
        if (n >= S_ANCH)
            out[(n - S_ANCH) * (size_t)(F_NUM * S_ANCH) + (size_t)tout * S_ANCH + s] = z;
    }
}

// ---------------- cost pieces ----------------
__global__ __launch_bounds__(256) void dot_reduce_kernel(const float* __restrict__ a,
                                                         const float* __restrict__ b,
                                                         float* __restrict__ outv, size_t n) {
    float s = 0.f;
    size_t idx = (size_t)blockIdx.x * blockDim.x + threadIdx.x;
    size_t stride = (size_t)gridDim.x * blockDim.x;
    for (size_t i = idx; i < n; i += stride) s += a[i] * b[i];
    for (int o = 32; o > 0; o >>= 1) s += __shfl_down(s, o);
    __shared__ float red[4];
    if ((threadIdx.x & 63) == 0) red[threadIdx.x >> 6] = s;
    __syncthreads();
    if (threadIdx.x == 0) atomicAdd(outv, red[0] + red[1] + red[2] + red[3]);
}

__global__ __launch_bounds__(256) void final_kernel(const float* __restrict__ cw,
                                                    const float* __restrict__ cb,
                                                    const float* __restrict__ cost,
                                                    float* __restrict__ out) {
    float s = 0.f;
    for (int i = threadIdx.x; i < 720; i += 256) s += cw[i] * cw[i];
    for (int i = threadIdx.x; i < 80; i += 256) s += cb[i] * cb[i];
    for (int o = 32; o > 0; o >>= 1) s += __shfl_down(s, o);
    __shared__ float red[4];
    if ((threadIdx.x & 63) == 0) red[threadIdx.x >> 6] = s;
    __syncthreads();
    if (threadIdx.x == 0) out[0] = red[0] + red[1] + red[2] + red[3] + cost[0] / 10.0f;
}

// ---------------- host ----------------
extern "C" void kernel_launch(void* const* d_in, const int* in_sizes, int n_in,
                              void* d_out, int out_size, void* d_ws, size_t ws_size,
                              hipStream_t stream) {
    (void)in_sizes; (void)n_in; (void)out_size; (void)ws_size;
    const float* data   = (const float*)d_in[0];
    const float* inputs = (const float*)d_in[1];
    const float* conv_w = (const float*)d_in[2];
    const float* conv_b = (const float*)d_in[3];
    const float* c_s    = (const float*)d_in[4];
    float* out = (float*)d_out;

    float* ws = (float*)d_ws;
    size_t off = 0;
    auto alloc = [&](size_t n) { float* p = ws + off; off += (n + 15) & ~(size_t)15; return p; };
    float* c_buf  = alloc(SD);
    float* psi    = alloc(ND);
    float* u      = alloc(ND);
    float* z_cur  = alloc(NS);
    float* z_tmp  = alloc(NS);
    float* accb   = alloc(NS);
    float* k_cur  = alloc(NS);
    float* tmpA   = alloc(SD);
    float* scl    = alloc(N_TOT);
    float* ah     = alloc(N_TOT);
    float* cost   = alloc(16);

    // time grid + cos tables (host, mirrors fp32 reference arithmetic)
    const double TAU_D = 6.2831853071795864769;
    float ts[F_NUM];
    for (int i = 0; i < F_NUM; i++) ts[i] = (float)((double)i / 9.0);
    float Wt[N_TV][F_NUM];
    for (int j = 0; j < N_TV; j++) {
        float t;
        if ((j & 1) == 0) t = ts[j >> 1];
        else {
            int i = j >> 1;
            float h = ts[i + 1] - ts[i];
            t = ts[i] + 0.5f * h;
        }
        for (int f = 0; f < F_NUM; f++) {
            float coeff = (float)(TAU_D * f);
            Wt[j][f] = (float)cos((double)t * (double)coeff);
        }
    }

    init_kernel<<<4096, 256, 0, stream>>>(z_cur, cost, out);

    const int conv_blocks = (int)(((size_t)N_TOT * 8 * 169 + 255) / 256);
    const int c_blocks = (int)((SD + 255) / 256);

    int cur_j = -1;
    for (int i = 0; i < 9; i++) {
        float h = ts[i + 1] - ts[i];
        int js[4] = {2 * i, 2 * i + 1, 2 * i + 1, 2 * i + 2};
        float alphas[3] = {0.5f * h, 0.5f * h, h};
        float coefs[4] = {1.f, 2.f, 2.f, 1.f};
        for (int e = 0; e < 4; e++) {
            int j = js[e];
            if (j != cur_j) {
                W10 w;
                for (int f = 0; f < F_NUM; f++) w.w[f] = Wt[j][f];
                compute_c_kernel<<<c_blocks, 256, 0, stream>>>(c_s, c_buf, w);
                conv_psi_kernel<<<conv_blocks, 256, 0, stream>>>(data, inputs, conv_w, conv_b, psi, w);
                cur_j = j;
            }
            const float* z_in = (e == 0) ? z_cur : z_tmp;
            gemm_nn_kernel<<<dim3(22, 48), 256, 0, stream>>>(z_in, c_buf, psi, u,
                                                             N_TOT, D_DIM, S_ANCH);
            rowstats_kernel<<<N_TOT, 256, 0, stream>>>(u, scl, ah);
            gemm_nt_kernel<<<dim3(16, 48), 256, 0, stream>>>(u, u, scl, ah, k_cur,
                                                             N_TOT, S_ANCH, D_DIM);
            if (e < 3)
                combine_kernel<<<4096, 256, 0, stream>>>(accb, z_tmp, z_cur, k_cur,
                                                         coefs[e], alphas[e], e == 0 ? 1 : 0);
            else
                finish_kernel<<<4096, 256, 0, stream>>>(z_cur, accb, k_cur, h / 6.0f,
                                                        out, i + 1);
        }
        // cost contribution at t = ts[i+1]: c_buf currently holds c_all[t]
        gemm_nn_kernel<<<dim3(22, 16), 256, 0, stream>>>(z_cur, c_buf, nullptr, tmpA,
                                                         S_ANCH, D_DIM, S_ANCH);
        dot_reduce_kernel<<<2048, 256, 0, stream>>>(tmpA, c_buf, cost, SD);
    }

    final_kernel<<<1, 256, 0, stream>>>(conv_w, conv_b, cost, out + OUT_Z);
}

// Round 2
// 5107.377 us; speedup vs baseline: 2.8259x; 2.8259x over previous
//
#include <hip/hip_runtime.h>
#include <math.h>

#define S_ANCH 1024
#define B_QRY  2048
#define N_TOT  3072
#define D_DIM  1352
#define D_PAD  1376   // K for GEMM2, multiple of 32
#define D_BPAD 1408   // c16T rows, multiple of 128
#define F_NUM  10
#define N_TV   19

static const size_t ND = (size_t)N_TOT * D_DIM;
static const size_t SD = (size_t)S_ANCH * D_DIM;
static const size_t NS = (size_t)N_TOT * S_ANCH;
static const size_t OUT_Z = (size_t)B_QRY * F_NUM * S_ANCH;

typedef __attribute__((ext_vector_type(8))) short bf16x8;
typedef __attribute__((ext_vector_type(4))) float f32x4;

struct W10 { float w[F_NUM]; };

__device__ inline unsigned short f2bf(float x) {
    unsigned int u = __builtin_bit_cast(unsigned int, x);
    unsigned int r = (u + 0x7FFFu + ((u >> 16) & 1u)) >> 16;
    return (unsigned short)r;
}

// ---------------- init: zero z, z16, cost, c16T pad rows, t=0 out slice ----------------
__global__ __launch_bounds__(256) void init_kernel(float* __restrict__ z,
                                                   unsigned short* __restrict__ z16,
                                                   float* __restrict__ cost,
                                                   unsigned short* __restrict__ c16T,
                                                   float* __restrict__ out) {
    size_t idx = (size_t)blockIdx.x * blockDim.x + threadIdx.x;
    size_t stride = (size_t)gridDim.x * blockDim.x;
    for (size_t i = idx; i < NS; i += stride) { z[i] = 0.f; z16[i] = 0; }
    const size_t NO = (size_t)B_QRY * S_ANCH;
    for (size_t i = idx; i < NO; i += stride) {
        size_t b = i >> 10, s = i & 1023;
        out[b * (size_t)(F_NUM * S_ANCH) + s] = 0.f;
    }
    // c16T pad rows [1352,1408)
    const size_t PADN = (size_t)(D_BPAD - D_DIM) * S_ANCH;
    for (size_t i = idx; i < PADN; i += stride)
        c16T[(size_t)D_DIM * S_ANCH + i] = 0;
    if (idx == 0) cost[0] = 0.f;
}

// ---------------- c_t: fp32 [S][D] + bf16 transposed [D_BPAD][S] ----------------
// grid (ceil(D/64)=22, S/32=32), block 256
__global__ __launch_bounds__(256) void compute_c_kernel(const float* __restrict__ cs,
                                                        float* __restrict__ cfp,
                                                        unsigned short* __restrict__ c16T,
                                                        W10 W) {
    __shared__ float tile[32][65];
    int d0 = blockIdx.x * 64, s0 = blockIdx.y * 32;
    int t = threadIdx.x;
    int d_l = t & 63, s_l0 = t >> 6;
    for (int ss = s_l0; ss < 32; ss += 4) {
        int d = d0 + d_l, s = s0 + ss;
        float v = 0.f;
        if (d < D_DIM) {
            const float* p = cs + ((size_t)s * D_DIM + d) * F_NUM;
#pragma unroll
            for (int f = 0; f < F_NUM; f++) v += p[f] * W.w[f];
            cfp[(size_t)s * D_DIM + d] = v;
        }
        tile[ss][d_l] = v;
    }
    __syncthreads();
    int s_l = t & 31, d_l1 = t >> 5;
    for (int dd = d_l1; dd < 64; dd += 8) {
        int d = d0 + dd;
        if (d < D_DIM)
            c16T[(size_t)d * S_ANCH + s0 + s_l] = f2bf(tile[s_l][dd]);
    }
}

// ---------------- psi_t[n,d] : conv fused with freq dot (fp32) ----------------
__global__ __launch_bounds__(256) void conv_psi_kernel(const float* __restrict__ data,
                                                       const float* __restrict__ inputs,
                                                       const float* __restrict__ cw,
                                                       const float* __restrict__ cb,
                                                       float* __restrict__ psi, W10 W) {
    __shared__ float wsh[720];
    __shared__ float bsh[80];
    for (int i = threadIdx.x; i < 720; i += 256) wsh[i] = cw[i];
    for (int i = threadIdx.x; i < 80; i += 256) bsh[i] = cb[i];
    __syncthreads();
    size_t idx = (size_t)blockIdx.x * 256 + threadIdx.x;
    if (idx >= (size_t)N_TOT * 8 * 169) return;
    int pos = (int)(idx % 169);
    int rest = (int)(idx / 169);
    int c8 = rest & 7;
    int n = rest >> 3;
    int oi = pos / 13, oj = pos % 13;
    const float* x = (n < S_ANCH) ? (data + (size_t)n * 784)
                                  : (inputs + (size_t)(n - S_ANCH) * 784);
    float vin[9];
#pragma unroll
    for (int kh = 0; kh < 3; kh++)
#pragma unroll
        for (int kw = 0; kw < 3; kw++)
            vin[kh * 3 + kw] = x[(2 * oi + kh) * 28 + (2 * oj + kw)];
    float p = 0.f;
#pragma unroll
    for (int f = 0; f < F_NUM; f++) {
        int co = f * 8 + c8;
        float s = bsh[co];
#pragma unroll
        for (int t = 0; t < 9; t++) s += vin[t] * wsh[co * 9 + t];
        p += s * W.w[f];
    }
    psi[(size_t)n * D_DIM + c8 * 169 + pos] = p;
}

// ---------------- MFMA GEMM (NT: A[M,K] rm, B[N,K] rm), 128x128 tile, BK=32 ----------------
struct GemmArgs {
    const unsigned short* A; const unsigned short* B;
    int lda, ldb, K;
    // MODE 0
    const float* psi; unsigned short* u16; float* rowsq;
    // MODE 1
    const float* scl; const float* ah;
    float* zcur; float* accb; unsigned short* zt16; float* outp;
    int first, finish, tout; float alpha, h6;
    // MODE 2
    const float* cfp; float* cost;
};

template<int MODE>
__global__ __launch_bounds__(256) void mfma_gemm(GemmArgs g) {
    __shared__ __align__(16) unsigned short As[128][40];
    __shared__ __align__(16) unsigned short Bs[128][40];
    __shared__ float red4[4];
    const int bm = blockIdx.y * 128, bn = blockIdx.x * 128;
    const int t = threadIdx.x;
    const int lane = t & 63, wv = t >> 6;
    const int wm = (wv >> 1) * 64, wn = (wv & 1) * 64;
    const int lr = lane & 15, lg = lane >> 4;

    const int q = t & 3;        // 16B chunk (8 bf16) within the 32-col row
    const int r0 = t >> 2;      // 0..63

    f32x4 acc[4][4];
#pragma unroll
    for (int i = 0; i < 4; i++)
#pragma unroll
        for (int j = 0; j < 4; j++) acc[i][j] = (f32x4){0.f, 0.f, 0.f, 0.f};

    int4 aR0, aR1, bR0, bR1;
    // preload k0=0
    {
        const unsigned short* Ap = g.A + (size_t)(bm + r0) * g.lda + q * 8;
        const unsigned short* Bp = g.B + (size_t)(bn + r0) * g.ldb + q * 8;
        aR0 = *(const int4*)Ap;
        aR1 = *(const int4*)(Ap + (size_t)64 * g.lda);
        bR0 = *(const int4*)Bp;
        bR1 = *(const int4*)(Bp + (size_t)64 * g.ldb);
    }
    for (int k0 = 0; k0 < g.K; k0 += 32) {
        __syncthreads();
        *(int4*)&As[r0][q * 8] = aR0;
        *(int4*)&As[r0 + 64][q * 8] = aR1;
        *(int4*)&Bs[r0][q * 8] = bR0;
        *(int4*)&Bs[r0 + 64][q * 8] = bR1;
        __syncthreads();
        if (k0 + 32 < g.K) {
            const unsigned short* Ap = g.A + (size_t)(bm + r0) * g.lda + k0 + 32 + q * 8;
            const unsigned short* Bp = g.B + (size_t)(bn + r0) * g.ldb + k0 + 32 + q * 8;
            aR0 = *(const int4*)Ap;
            aR1 = *(const int4*)(Ap + (size_t)64 * g.lda);
            bR0 = *(const int4*)Bp;
            bR1 = *(const int4*)(Bp + (size_t)64 * g.ldb);
        }
        bf16x8 af[4], bf[4];
#pragma unroll
        for (int i = 0; i < 4; i++)
            af[i] = *(const bf16x8*)&As[wm + i * 16 + lr][lg * 8];
#pragma unroll
        for (int j = 0; j < 4; j++)
            bf[j] = *(const bf16x8*)&Bs[wn + j * 16 + lr][lg * 8];
#pragma unroll
        for (int i = 0; i < 4; i++)
#pragma unroll
            for (int j = 0; j < 4; j++)
                acc[i][j] = __builtin_amdgcn_mfma_f32_16x16x32_bf16(af[i], bf[j], acc[i][j], 0, 0, 0);
    }

    // ---------------- epilogues ----------------
    if (MODE == 0) {
        // u = acc + psi ; write u16 (bf16, D_PAD stride) ; rowsq atomics (fp32, pre-rounding)
#pragma unroll
        for (int i = 0; i < 4; i++) {
#pragma unroll
            for (int reg = 0; reg < 4; reg++) {
                int m = bm + wm + i * 16 + lg * 4 + reg;
                float sq = 0.f;
#pragma unroll
                for (int j = 0; j < 4; j++) {
                    int n = bn + wn + j * 16 + lr;
                    float v = acc[i][j][reg];
                    if (n < D_DIM) v += g.psi[(size_t)m * D_DIM + n];
                    else v = 0.f;
                    if (n < D_PAD) g.u16[(size_t)m * D_PAD + n] = f2bf(v);
                    sq += v * v;
                }
                sq += __shfl_xor(sq, 1);
                sq += __shfl_xor(sq, 2);
                sq += __shfl_xor(sq, 4);
                sq += __shfl_xor(sq, 8);
                if (lr == 0) atomicAdd(&g.rowsq[m], sq);
            }
        }
    } else if (MODE == 1) {
        // kernel epilogue + fused RK4 bookkeeping
#pragma unroll
        for (int i = 0; i < 4; i++) {
#pragma unroll
            for (int reg = 0; reg < 4; reg++) {
                int m = bm + wm + i * 16 + lg * 4 + reg;
                float sm = g.scl[m], am = g.ah[m];
#pragma unroll
                for (int j = 0; j < 4; j++) {
                    int n = bn + wn + j * 16 + lr;
                    float uv = acc[i][j][reg] * sm * g.scl[n];
                    float kv = __expf(uv - am - g.ah[n]) * uv;
                    size_t idx = (size_t)m * S_ANCH + n;
                    if (!g.finish) {
                        if (g.first) g.accb[idx] = kv;
                        else g.accb[idx] += 2.0f * kv;
                        float zt = g.zcur[idx] + g.alpha * kv;
                        g.zt16[idx] = f2bf(zt);
                    } else {
                        float z = g.zcur[idx] + g.h6 * (g.accb[idx] + kv);
                        g.zcur[idx] = z;
                        g.zt16[idx] = f2bf(z);
                        if (m >= S_ANCH)
                            g.outp[(size_t)(m - S_ANCH) * (F_NUM * S_ANCH)
                                   + (size_t)g.tout * S_ANCH + n] = z;
                    }
                }
            }
        }
    } else {
        // cost: sum acc[m,n] * cfp[m,n]
        float s = 0.f;
#pragma unroll
        for (int i = 0; i < 4; i++)
#pragma unroll
            for (int reg = 0; reg < 4; reg++) {
                int m = bm + wm + i * 16 + lg * 4 + reg;
#pragma unroll
                for (int j = 0; j < 4; j++) {
                    int n = bn + wn + j * 16 + lr;
                    if (n < D_DIM) s += acc[i][j][reg] * g.cfp[(size_t)m * D_DIM + n];
                }
            }
        s += __shfl_xor(s, 1); s += __shfl_xor(s, 2); s += __shfl_xor(s, 4);
        s += __shfl_xor(s, 8); s += __shfl_xor(s, 16); s += __shfl_xor(s, 32);
        if (lane == 0) red4[wv] = s;
        __syncthreads();
        if (t == 0) atomicAdd(g.cost, red4[0] + red4[1] + red4[2] + red4[3]);
    }
}

// ---------------- squash stats from rowsq ----------------
__global__ __launch_bounds__(256) void stats_kernel(const float* __restrict__ rowsq,
                                                    float* __restrict__ scl,
                                                    float* __restrict__ ah) {
    int n = blockIdx.x * 256 + threadIdx.x;
    if (n >= N_TOT) return;
    float tot = rowsq[n];
    float norm = sqrtf(tot + 1e-6f);
    float sg = 1.f / (1.f + expf(-norm));
    float sc = sg / norm;
    scl[n] = sc;
    ah[n] = 0.5f * tot * sc * sc;
}

// ---------------- final: add conv_w/b square norm ----------------
__global__ __launch_bounds__(256) void final_kernel(const float* __restrict__ cw,
                                                    const float* __restrict__ cb,
                                                    const float* __restrict__ cost,
                                                    float* __restrict__ out) {
    float s = 0.f;
    for (int i = threadIdx.x; i < 720; i += 256) s += cw[i] * cw[i];
    for (int i = threadIdx.x; i < 80; i += 256) s += cb[i] * cb[i];
    for (int o = 32; o > 0; o >>= 1) s += __shfl_down(s, o);
    __shared__ float red[4];
    if ((threadIdx.x & 63) == 0) red[threadIdx.x >> 6] = s;
    __syncthreads();
    if (threadIdx.x == 0) out[0] = red[0] + red[1] + red[2] + red[3] + cost[0] / 10.0f;
}

// ---------------- host ----------------
extern "C" void kernel_launch(void* const* d_in, const int* in_sizes, int n_in,
                              void* d_out, int out_size, void* d_ws, size_t ws_size,
                              hipStream_t stream) {
    (void)in_sizes; (void)n_in; (void)out_size; (void)ws_size;
    const float* data   = (const float*)d_in[0];
    const float* inputs = (const float*)d_in[1];
    const float* conv_w = (const float*)d_in[2];
    const float* conv_b = (const float*)d_in[3];
    const float* c_s    = (const float*)d_in[4];
    float* out = (float*)d_out;

    char* ws = (char*)d_ws;
    size_t off = 0;
    auto alloc = [&](size_t bytes) {
        char* p = ws + off; off += (bytes + 255) & ~(size_t)255; return p;
    };
    float*          c_buf = (float*)alloc(SD * 4);
    unsigned short* c16T  = (unsigned short*)alloc((size_t)D_BPAD * S_ANCH * 2);
    float*          psi   = (float*)alloc(ND * 4);
    unsigned short* u16   = (unsigned short*)alloc((size_t)N_TOT * D_PAD * 2);
    float*          z_cur = (float*)alloc(NS * 4);
    unsigned short* z16   = (unsigned short*)alloc(NS * 2);
    unsigned short* zt16  = (unsigned short*)alloc(NS * 2);
    float*          accb  = (float*)alloc(NS * 4);
    float*          rowsq = (float*)alloc(N_TOT * 4);
    float*          scl   = (float*)alloc(N_TOT * 4);
    float*          ah    = (float*)alloc(N_TOT * 4);
    float*          cost  = (float*)alloc(64);

    const double TAU_D = 6.2831853071795864769;
    float ts[F_NUM];
    for (int i = 0; i < F_NUM; i++) ts[i] = (float)((double)i / 9.0);
    float Wt[N_TV][F_NUM];
    for (int j = 0; j < N_TV; j++) {
        float tt;
        if ((j & 1) == 0) tt = ts[j >> 1];
        else {
            int i = j >> 1;
            float h = ts[i + 1] - ts[i];
            tt = ts[i] + 0.5f * h;
        }
        for (int f = 0; f < F_NUM; f++) {
            float coeff = (float)(TAU_D * f);
            float targ = tt * coeff;
            Wt[j][f] = (float)cos((double)targ);
        }
    }

    init_kernel<<<2048, 256, 0, stream>>>(z_cur, z16, cost, c16T, out);

    const int conv_blocks = (int)(((size_t)N_TOT * 8 * 169 + 255) / 256);

    GemmArgs g0 = {}; // GEMM1
    g0.B = c16T; g0.lda = S_ANCH; g0.ldb = S_ANCH; g0.K = S_ANCH;
    g0.psi = psi; g0.u16 = u16; g0.rowsq = rowsq;
    GemmArgs g1 = {}; // GEMM2
    g1.A = u16; g1.B = u16; g1.lda = D_PAD; g1.ldb = D_PAD; g1.K = D_PAD;
    g1.scl = scl; g1.ah = ah; g1.zcur = z_cur; g1.accb = accb;
    GemmArgs g2 = {}; // cost
    g2.A = z16; g2.B = c16T; g2.lda = S_ANCH; g2.ldb = S_ANCH; g2.K = S_ANCH;
    g2.cfp = c_buf; g2.cost = cost;

    int cur_j = -1;
    for (int i = 0; i < 9; i++) {
        float h = ts[i + 1] - ts[i];
        int js[4] = {2 * i, 2 * i + 1, 2 * i + 1, 2 * i + 2};
        float alphas[3] = {0.5f * h, 0.5f * h, h};
        for (int e = 0; e < 4; e++) {
            int j = js[e];
            if (j != cur_j) {
                W10 w;
                for (int f = 0; f < F_NUM; f++) w.w[f] = Wt[j][f];
                compute_c_kernel<<<dim3(22, 32), 256, 0, stream>>>(c_s, c_buf, c16T, w);
                conv_psi_kernel<<<conv_blocks, 256, 0, stream>>>(data, inputs, conv_w, conv_b, psi, w);
                cur_j = j;
            }
            hipMemsetAsync(rowsq, 0, N_TOT * sizeof(float), stream);
            g0.A = (e == 0) ? z16 : zt16;
            mfma_gemm<0><<<dim3(11, 24), 256, 0, stream>>>(g0);
            stats_kernel<<<12, 256, 0, stream>>>(rowsq, scl, ah);
            g1.first = (e == 0); g1.finish = (e == 3);
            g1.alpha = (e < 3) ? alphas[e] : 0.f;
            g1.h6 = h / 6.0f; g1.tout = i + 1;
            g1.zt16 = (e < 3) ? zt16 : z16;
            g1.outp = out;
            mfma_gemm<1><<<dim3(8, 24), 256, 0, stream>>>(g1);
        }
        mfma_gemm<2><<<dim3(11, 8), 256, 0, stream>>>(g2);
    }

    final_kernel<<<1, 256, 0, stream>>>(conv_w, conv_b, cost, out + OUT_Z);
}

// Round 3
// 4980.486 us; speedup vs baseline: 2.8979x; 1.0255x over previous
//
#include <hip/hip_runtime.h>
#include <math.h>

#define S_ANCH 1024
#define B_QRY  2048
#define N_TOT  3072
#define D_DIM  1352
#define D_PAD  1376   // K for GEMM2, multiple of 32
#define D_BPAD 1408   // c16T rows, multiple of 128
#define F_NUM  10
#define N_TV   19
#define NPART  22     // 11 n-tiles * 2 wave-halves in GEMM1

static const size_t ND = (size_t)N_TOT * D_DIM;
static const size_t SD = (size_t)S_ANCH * D_DIM;
static const size_t NS = (size_t)N_TOT * S_ANCH;
static const size_t OUT_Z = (size_t)B_QRY * F_NUM * S_ANCH;

typedef __attribute__((ext_vector_type(8))) short bf16x8;
typedef __attribute__((ext_vector_type(4))) float f32x4;

struct W10 { float w[F_NUM]; };

__device__ inline unsigned short f2bf(float x) {
    unsigned int u = __builtin_bit_cast(unsigned int, x);
    unsigned int r = (u + 0x7FFFu + ((u >> 16) & 1u)) >> 16;
    return (unsigned short)r;
}

__device__ __forceinline__ void stage16(const unsigned short* gp, unsigned short* lp) {
    __builtin_amdgcn_global_load_lds(
        (const __attribute__((address_space(1))) unsigned int*)(const void*)gp,
        (__attribute__((address_space(3))) unsigned int*)(void*)lp, 16, 0, 0);
}

// ---------------- init: zero z, z16, cost, c16T pad rows, t=0 out slice ----------------
__global__ __launch_bounds__(256) void init_kernel(float* __restrict__ z,
                                                   unsigned short* __restrict__ z16,
                                                   float* __restrict__ cost,
                                                   unsigned short* __restrict__ c16T,
                                                   float* __restrict__ out) {
    size_t idx = (size_t)blockIdx.x * blockDim.x + threadIdx.x;
    size_t stride = (size_t)gridDim.x * blockDim.x;
    for (size_t i = idx; i < NS; i += stride) { z[i] = 0.f; z16[i] = 0; }
    const size_t NO = (size_t)B_QRY * S_ANCH;
    for (size_t i = idx; i < NO; i += stride) {
        size_t b = i >> 10, s = i & 1023;
        out[b * (size_t)(F_NUM * S_ANCH) + s] = 0.f;
    }
    const size_t PADN = (size_t)(D_BPAD - D_DIM) * S_ANCH;
    for (size_t i = idx; i < PADN; i += stride)
        c16T[(size_t)D_DIM * S_ANCH + i] = 0;
    if (idx == 0) cost[0] = 0.f;
}

// ---------------- c_t: fp32 [S][D] + bf16 transposed [D_BPAD][S] ----------------
__global__ __launch_bounds__(256) void compute_c_kernel(const float* __restrict__ cs,
                                                        float* __restrict__ cfp,
                                                        unsigned short* __restrict__ c16T,
                                                        W10 W) {
    __shared__ float tile[32][65];
    int d0 = blockIdx.x * 64, s0 = blockIdx.y * 32;
    int t = threadIdx.x;
    int d_l = t & 63, s_l0 = t >> 6;
    for (int ss = s_l0; ss < 32; ss += 4) {
        int d = d0 + d_l, s = s0 + ss;
        float v = 0.f;
        if (d < D_DIM) {
            const float* p = cs + ((size_t)s * D_DIM + d) * F_NUM;
#pragma unroll
            for (int f = 0; f < F_NUM; f++) v += p[f] * W.w[f];
            cfp[(size_t)s * D_DIM + d] = v;
        }
        tile[ss][d_l] = v;
    }
    __syncthreads();
    int s_l = t & 31, d_l1 = t >> 5;
    for (int dd = d_l1; dd < 64; dd += 8) {
        int d = d0 + dd;
        if (d < D_DIM)
            c16T[(size_t)d * S_ANCH + s0 + s_l] = f2bf(tile[s_l][dd]);
    }
}

// ---------------- psi_t[n,d] : conv fused with freq dot (fp32) ----------------
__global__ __launch_bounds__(256) void conv_psi_kernel(const float* __restrict__ data,
                                                       const float* __restrict__ inputs,
                                                       const float* __restrict__ cw,
                                                       const float* __restrict__ cb,
                                                       float* __restrict__ psi, W10 W) {
    __shared__ float wsh[720];
    __shared__ float bsh[80];
    for (int i = threadIdx.x; i < 720; i += 256) wsh[i] = cw[i];
    for (int i = threadIdx.x; i < 80; i += 256) bsh[i] = cb[i];
    __syncthreads();
    size_t idx = (size_t)blockIdx.x * 256 + threadIdx.x;
    if (idx >= (size_t)N_TOT * 8 * 169) return;
    int pos = (int)(idx % 169);
    int rest = (int)(idx / 169);
    int c8 = rest & 7;
    int n = rest >> 3;
    int oi = pos / 13, oj = pos % 13;
    const float* x = (n < S_ANCH) ? (data + (size_t)n * 784)
                                  : (inputs + (size_t)(n - S_ANCH) * 784);
    float vin[9];
#pragma unroll
    for (int kh = 0; kh < 3; kh++)
#pragma unroll
        for (int kw = 0; kw < 3; kw++)
            vin[kh * 3 + kw] = x[(2 * oi + kh) * 28 + (2 * oj + kw)];
    float p = 0.f;
#pragma unroll
    for (int f = 0; f < F_NUM; f++) {
        int co = f * 8 + c8;
        float s = bsh[co];
#pragma unroll
        for (int t = 0; t < 9; t++) s += vin[t] * wsh[co * 9 + t];
        p += s * W.w[f];
    }
    psi[(size_t)n * D_DIM + c8 * 169 + pos] = p;
}

// ---------------- MFMA GEMM (NT), 128x128 tile, BK=32, 2-phase gload_lds ----------------
struct GemmArgs {
    const unsigned short* A; const unsigned short* B;
    int lda, ldb, K;
    // MODE 0
    const float* psi; unsigned short* u16; float* rowsqP;
    // MODE 1
    float* zcur; float* accb; unsigned short* zt16; float* outp;
    int first, finish, tout; float alpha, h6;
    // MODE 2
    const float* cfp; float* cost;
};

template<int MODE>
__global__ __launch_bounds__(256) void mfma_gemm(GemmArgs g) {
    __shared__ __align__(16) unsigned short As[2][128][32];
    __shared__ __align__(16) unsigned short Bs[2][128][32];
    __shared__ float sclM[128], ahM[128], sclN[128], ahN[128];
    __shared__ float red4[4];
    const int bm = blockIdx.y * 128, bn = blockIdx.x * 128;
    const int t = threadIdx.x;
    const int lane = t & 63, wv = t >> 6;
    const int wm = (wv >> 1) * 64, wn = (wv & 1) * 64;
    const int lr = lane & 15, lg = lane >> 4;
    const int srow = lane >> 2, scol = (lane & 3) << 3;

    if (MODE == 1) {
        // inline squash stats from GEMM1's partial row sums (no extra dispatch)
        int r = (t < 128) ? (bm + t) : (bn + (t - 128));
        float tot = 0.f;
#pragma unroll
        for (int c = 0; c < NPART; c++) tot += g.rowsqP[(size_t)c * N_TOT + r];
        float norm = sqrtf(tot + 1e-6f);
        float sg = 1.f / (1.f + __expf(-norm));
        float sc = sg / norm;
        float a = 0.5f * tot * sc * sc;
        if (t < 128) { sclM[t] = sc; ahM[t] = a; }
        else         { sclN[t - 128] = sc; ahN[t - 128] = a; }
    }

    f32x4 acc[4][4];
#pragma unroll
    for (int i = 0; i < 4; i++)
#pragma unroll
        for (int j = 0; j < 4; j++) acc[i][j] = (f32x4){0.f, 0.f, 0.f, 0.f};

    const unsigned short* Abase = g.A + (size_t)(bm + wv * 16 + srow) * g.lda + scol;
    const unsigned short* Bbase = g.B + (size_t)(bn + wv * 16 + srow) * g.ldb + scol;
    const size_t a64 = (size_t)64 * g.lda, b64 = (size_t)64 * g.ldb;

    auto STAGE = [&](int kk, int buf) {
        stage16(Abase + kk,       &As[buf][wv * 16][0]);
        stage16(Abase + kk + a64, &As[buf][64 + wv * 16][0]);
        stage16(Bbase + kk,       &Bs[buf][wv * 16][0]);
        stage16(Bbase + kk + b64, &Bs[buf][64 + wv * 16][0]);
    };
    auto COMPUTE = [&](int buf) {
        bf16x8 af[4], bf[4];
#pragma unroll
        for (int i = 0; i < 4; i++)
            af[i] = *(const bf16x8*)&As[buf][wm + i * 16 + lr][lg * 8];
#pragma unroll
        for (int j = 0; j < 4; j++)
            bf[j] = *(const bf16x8*)&Bs[buf][wn + j * 16 + lr][lg * 8];
#pragma unroll
        for (int i = 0; i < 4; i++)
#pragma unroll
            for (int j = 0; j < 4; j++)
                acc[i][j] = __builtin_amdgcn_mfma_f32_16x16x32_bf16(af[i], bf[j], acc[i][j], 0, 0, 0);
    };

    const int nt = g.K >> 5;
    STAGE(0, 0);
    asm volatile("s_waitcnt vmcnt(0) lgkmcnt(0)" ::: "memory");
    __builtin_amdgcn_s_barrier();
    __builtin_amdgcn_sched_barrier(0);
    int cur = 0;
    for (int tt = 0; tt < nt - 1; ++tt) {
        STAGE((tt + 1) << 5, cur ^ 1);
        COMPUTE(cur);
        asm volatile("s_waitcnt vmcnt(0)" ::: "memory");
        __builtin_amdgcn_s_barrier();
        __builtin_amdgcn_sched_barrier(0);
        cur ^= 1;
    }
    COMPUTE(cur);

    // ---------------- epilogues ----------------
    if (MODE == 0) {
#pragma unroll
        for (int i = 0; i < 4; i++) {
#pragma unroll
            for (int reg = 0; reg < 4; reg++) {
                int m = bm + wm + i * 16 + lg * 4 + reg;
                float sq = 0.f;
#pragma unroll
                for (int j = 0; j < 4; j++) {
                    int n = bn + wn + j * 16 + lr;
                    float v = acc[i][j][reg];
                    if (n < D_DIM) v += g.psi[(size_t)m * D_DIM + n];
                    else v = 0.f;
                    if (n < D_PAD) g.u16[(size_t)m * D_PAD + n] = f2bf(v);
                    sq += v * v;
                }
                sq += __shfl_xor(sq, 1);
                sq += __shfl_xor(sq, 2);
                sq += __shfl_xor(sq, 4);
                sq += __shfl_xor(sq, 8);
                if (lr == 0)
                    g.rowsqP[(size_t)(blockIdx.x * 2 + (wn >> 6)) * N_TOT + m] = sq;
            }
        }
    } else if (MODE == 1) {
#pragma unroll
        for (int i = 0; i < 4; i++) {
#pragma unroll
            for (int reg = 0; reg < 4; reg++) {
                int mi = wm + i * 16 + lg * 4 + reg;
                int m = bm + mi;
                float sm = sclM[mi], am = ahM[mi];
#pragma unroll
                for (int j = 0; j < 4; j++) {
                    int ni = wn + j * 16 + lr;
                    int n = bn + ni;
                    float uv = acc[i][j][reg] * sm * sclN[ni];
                    float kv = __expf(uv - am - ahN[ni]) * uv;
                    size_t idx = (size_t)m * S_ANCH + n;
                    if (!g.finish) {
                        if (g.first) g.accb[idx] = kv;
                        else g.accb[idx] += 2.0f * kv;
                        float zt = g.zcur[idx] + g.alpha * kv;
                        g.zt16[idx] = f2bf(zt);
                    } else {
                        float z = g.zcur[idx] + g.h6 * (g.accb[idx] + kv);
                        g.zcur[idx] = z;
                        g.zt16[idx] = f2bf(z);
                        if (m >= S_ANCH)
                            g.outp[(size_t)(m - S_ANCH) * (F_NUM * S_ANCH)
                                   + (size_t)g.tout * S_ANCH + n] = z;
                    }
                }
            }
        }
    } else {
        float s = 0.f;
#pragma unroll
        for (int i = 0; i < 4; i++)
#pragma unroll
            for (int reg = 0; reg < 4; reg++) {
                int m = bm + wm + i * 16 + lg * 4 + reg;
#pragma unroll
                for (int j = 0; j < 4; j++) {
                    int n = bn + wn + j * 16 + lr;
                    if (n < D_DIM) s += acc[i][j][reg] * g.cfp[(size_t)m * D_DIM + n];
                }
            }
        s += __shfl_xor(s, 1); s += __shfl_xor(s, 2); s += __shfl_xor(s, 4);
        s += __shfl_xor(s, 8); s += __shfl_xor(s, 16); s += __shfl_xor(s, 32);
        if (lane == 0) red4[wv] = s;
        __syncthreads();
        if (t == 0) atomicAdd(g.cost, red4[0] + red4[1] + red4[2] + red4[3]);
    }
}

// ---------------- final: add conv_w/b square norm ----------------
__global__ __launch_bounds__(256) void final_kernel(const float* __restrict__ cw,
                                                    const float* __restrict__ cb,
                                                    const float* __restrict__ cost,
                                                    float* __restrict__ out) {
    float s = 0.f;
    for (int i = threadIdx.x; i < 720; i += 256) s += cw[i] * cw[i];
    for (int i = threadIdx.x; i < 80; i += 256) s += cb[i] * cb[i];
    for (int o = 32; o > 0; o >>= 1) s += __shfl_down(s, o);
    __shared__ float red[4];
    if ((threadIdx.x & 63) == 0) red[threadIdx.x >> 6] = s;
    __syncthreads();
    if (threadIdx.x == 0) out[0] = red[0] + red[1] + red[2] + red[3] + cost[0] / 10.0f;
}

// ---------------- host ----------------
extern "C" void kernel_launch(void* const* d_in, const int* in_sizes, int n_in,
                              void* d_out, int out_size, void* d_ws, size_t ws_size,
                              hipStream_t stream) {
    (void)in_sizes; (void)n_in; (void)out_size; (void)ws_size;
    const float* data   = (const float*)d_in[0];
    const float* inputs = (const float*)d_in[1];
    const float* conv_w = (const float*)d_in[2];
    const float* conv_b = (const float*)d_in[3];
    const float* c_s    = (const float*)d_in[4];
    float* out = (float*)d_out;

    char* ws = (char*)d_ws;
    size_t off = 0;
    auto alloc = [&](size_t bytes) {
        char* p = ws + off; off += (bytes + 255) & ~(size_t)255; return p;
    };
    float*          c_buf  = (float*)alloc(SD * 4);
    unsigned short* c16T   = (unsigned short*)alloc((size_t)D_BPAD * S_ANCH * 2);
    float*          psi    = (float*)alloc(ND * 4);
    unsigned short* u16    = (unsigned short*)alloc((size_t)N_TOT * D_PAD * 2);
    float*          z_cur  = (float*)alloc(NS * 4);
    unsigned short* z16    = (unsigned short*)alloc(NS * 2);
    unsigned short* zt16   = (unsigned short*)alloc(NS * 2);
    float*          accb   = (float*)alloc(NS * 4);
    float*          rowsqP = (float*)alloc((size_t)NPART * N_TOT * 4);
    float*          cost   = (float*)alloc(64);

    const double TAU_D = 6.2831853071795864769;
    float ts[F_NUM];
    for (int i = 0; i < F_NUM; i++) ts[i] = (float)((double)i / 9.0);
    float Wt[N_TV][F_NUM];
    for (int j = 0; j < N_TV; j++) {
        float tt;
        if ((j & 1) == 0) tt = ts[j >> 1];
        else {
            int i = j >> 1;
            float h = ts[i + 1] - ts[i];
            tt = ts[i] + 0.5f * h;
        }
        for (int f = 0; f < F_NUM; f++) {
            float coeff = (float)(TAU_D * f);
            float targ = tt * coeff;
            Wt[j][f] = (float)cos((double)targ);
        }
    }

    init_kernel<<<2048, 256, 0, stream>>>(z_cur, z16, cost, c16T, out);

    const int conv_blocks = (int)(((size_t)N_TOT * 8 * 169 + 255) / 256);

    GemmArgs g0 = {}; // GEMM1: u = z@cT + psi
    g0.B = c16T; g0.lda = S_ANCH; g0.ldb = S_ANCH; g0.K = S_ANCH;
    g0.psi = psi; g0.u16 = u16; g0.rowsqP = rowsqP;
    GemmArgs g1 = {}; // GEMM2: kernel + RK4 bookkeeping
    g1.A = u16; g1.B = u16; g1.lda = D_PAD; g1.ldb = D_PAD; g1.K = D_PAD;
    g1.zcur = z_cur; g1.accb = accb; g1.rowsqP = rowsqP;
    GemmArgs g2 = {}; // cost quadratic form
    g2.A = z16; g2.B = c16T; g2.lda = S_ANCH; g2.ldb = S_ANCH; g2.K = S_ANCH;
    g2.cfp = c_buf; g2.cost = cost;

    int cur_j = -1;
    for (int i = 0; i < 9; i++) {
        float h = ts[i + 1] - ts[i];
        int js[4] = {2 * i, 2 * i + 1, 2 * i + 1, 2 * i + 2};
        float alphas[3] = {0.5f * h, 0.5f * h, h};
        for (int e = 0; e < 4; e++) {
            int j = js[e];
            if (j != cur_j) {
                W10 w;
                for (int f = 0; f < F_NUM; f++) w.w[f] = Wt[j][f];
                compute_c_kernel<<<dim3(22, 32), 256, 0, stream>>>(c_s, c_buf, c16T, w);
                conv_psi_kernel<<<conv_blocks, 256, 0, stream>>>(data, inputs, conv_w, conv_b, psi, w);
                cur_j = j;
            }
            g0.A = (e == 0) ? z16 : zt16;
            mfma_gemm<0><<<dim3(11, 24), 256, 0, stream>>>(g0);
            g1.first = (e == 0); g1.finish = (e == 3);
            g1.alpha = (e < 3) ? alphas[e] : 0.f;
            g1.h6 = h / 6.0f; g1.tout = i + 1;
            g1.zt16 = (e < 3) ? zt16 : z16;
            g1.outp = out;
            mfma_gemm<1><<<dim3(8, 24), 256, 0, stream>>>(g1);
        }
        mfma_gemm<2><<<dim3(11, 8), 256, 0, stream>>>(g2);
    }

    final_kernel<<<1, 256, 0, stream>>>(conv_w, conv_b, cost, out + OUT_Z);
}

// Round 4
// 3752.668 us; speedup vs baseline: 3.8461x; 1.3272x over previous
//
#include <hip/hip_runtime.h>
#include <math.h>

#define S_ANCH 1024
#define B_QRY  2048
#define N_TOT  3072
#define D_DIM  1352
#define D_PAD  1376   // K for GEMM2, multiple of 32
#define D_BPAD 1408   // c16T rows, multiple of 128
#define F_NUM  10
#define N_TV   19
#define NPART  22     // 11 n-tiles * 2 wave-halves in GEMM1

static const size_t ND = (size_t)N_TOT * D_DIM;
static const size_t SD = (size_t)S_ANCH * D_DIM;
static const size_t NS = (size_t)N_TOT * S_ANCH;
static const size_t OUT_Z = (size_t)B_QRY * F_NUM * S_ANCH;

typedef __attribute__((ext_vector_type(8))) short bf16x8;
typedef __attribute__((ext_vector_type(4))) float f32x4;

struct W10 { float w[F_NUM]; };

__device__ inline unsigned short f2bf(float x) {
    unsigned int u = __builtin_bit_cast(unsigned int, x);
    unsigned int r = (u + 0x7FFFu + ((u >> 16) & 1u)) >> 16;
    return (unsigned short)r;
}

__device__ __forceinline__ void stage16(const unsigned short* gp, unsigned short* lp) {
    __builtin_amdgcn_global_load_lds(
        (const __attribute__((address_space(1))) unsigned int*)(const void*)gp,
        (__attribute__((address_space(3))) unsigned int*)(void*)lp, 16, 0, 0);
}

// ---------------- init: zero z, z16, cost, c16T pad rows, t=0 out slice ----------------
__global__ __launch_bounds__(256) void init_kernel(float* __restrict__ z,
                                                   unsigned short* __restrict__ z16,
                                                   float* __restrict__ cost,
                                                   unsigned short* __restrict__ c16T,
                                                   float* __restrict__ out) {
    size_t idx = (size_t)blockIdx.x * blockDim.x + threadIdx.x;
    size_t stride = (size_t)gridDim.x * blockDim.x;
    for (size_t i = idx; i < NS; i += stride) { z[i] = 0.f; z16[i] = 0; }
    const size_t NO = (size_t)B_QRY * S_ANCH;
    for (size_t i = idx; i < NO; i += stride) {
        size_t b = i >> 10, s = i & 1023;
        out[b * (size_t)(F_NUM * S_ANCH) + s] = 0.f;
    }
    const size_t PADN = (size_t)(D_BPAD - D_DIM) * S_ANCH;
    for (size_t i = idx; i < PADN; i += stride)
        c16T[(size_t)D_DIM * S_ANCH + i] = 0;
    if (idx == 0) cost[0] = 0.f;
}

// ---------------- c_t: fp32 [S][D] + bf16 transposed [D_BPAD][S] ----------------
__global__ __launch_bounds__(256) void compute_c_kernel(const float* __restrict__ cs,
                                                        float* __restrict__ cfp,
                                                        unsigned short* __restrict__ c16T,
                                                        W10 W) {
    __shared__ float tile[32][65];
    int d0 = blockIdx.x * 64, s0 = blockIdx.y * 32;
    int t = threadIdx.x;
    int d_l = t & 63, s_l0 = t >> 6;
    for (int ss = s_l0; ss < 32; ss += 4) {
        int d = d0 + d_l, s = s0 + ss;
        float v = 0.f;
        if (d < D_DIM) {
            const float* p = cs + ((size_t)s * D_DIM + d) * F_NUM;
#pragma unroll
            for (int f = 0; f < F_NUM; f++) v += p[f] * W.w[f];
            cfp[(size_t)s * D_DIM + d] = v;
        }
        tile[ss][d_l] = v;
    }
    __syncthreads();
    int s_l = t & 31, d_l1 = t >> 5;
    for (int dd = d_l1; dd < 64; dd += 8) {
        int d = d0 + dd;
        if (d < D_DIM)
            c16T[(size_t)d * S_ANCH + s0 + s_l] = f2bf(tile[s_l][dd]);
    }
}

// ---------------- psi_t[n,d] : conv fused with freq dot (fp32) ----------------
__global__ __launch_bounds__(256) void conv_psi_kernel(const float* __restrict__ data,
                                                       const float* __restrict__ inputs,
                                                       const float* __restrict__ cw,
                                                       const float* __restrict__ cb,
                                                       float* __restrict__ psi, W10 W) {
    __shared__ float wsh[720];
    __shared__ float bsh[80];
    for (int i = threadIdx.x; i < 720; i += 256) wsh[i] = cw[i];
    for (int i = threadIdx.x; i < 80; i += 256) bsh[i] = cb[i];
    __syncthreads();
    size_t idx = (size_t)blockIdx.x * 256 + threadIdx.x;
    if (idx >= (size_t)N_TOT * 8 * 169) return;
    int pos = (int)(idx % 169);
    int rest = (int)(idx / 169);
    int c8 = rest & 7;
    int n = rest >> 3;
    int oi = pos / 13, oj = pos % 13;
    const float* x = (n < S_ANCH) ? (data + (size_t)n * 784)
                                  : (inputs + (size_t)(n - S_ANCH) * 784);
    float vin[9];
#pragma unroll
    for (int kh = 0; kh < 3; kh++)
#pragma unroll
        for (int kw = 0; kw < 3; kw++)
            vin[kh * 3 + kw] = x[(2 * oi + kh) * 28 + (2 * oj + kw)];
    float p = 0.f;
#pragma unroll
    for (int f = 0; f < F_NUM; f++) {
        int co = f * 8 + c8;
        float s = bsh[co];
#pragma unroll
        for (int t = 0; t < 9; t++) s += vin[t] * wsh[co * 9 + t];
        p += s * W.w[f];
    }
    psi[(size_t)n * D_DIM + c8 * 169 + pos] = p;
}

// ---------------- MFMA GEMM (NT), 64x128 tile, BK=32, 2-phase gload_lds ----------------
// 4 waves; wave (wv>>1, wv&1) owns a 32x64 sub-tile: acc[2][4].
struct GemmArgs {
    const unsigned short* A; const unsigned short* B;
    int lda, ldb, K;
    // MODE 0
    const float* psi; unsigned short* u16; float* rowsqP;
    // MODE 1
    float* zcur; float* accb; unsigned short* zt16; float* outp;
    int first, finish, tout; float alpha, h6;
    // MODE 2
    const float* cfp; float* cost;
};

template<int MODE>
__global__ __launch_bounds__(256) void mfma_gemm(GemmArgs g) {
    __shared__ __align__(16) unsigned short As[2][64][32];
    __shared__ __align__(16) unsigned short Bs[2][128][32];
    __shared__ float sclM[64], ahM[64], sclN[128], ahN[128];
    __shared__ float red4[4];
    const int bm = blockIdx.y * 64, bn = blockIdx.x * 128;
    const int t = threadIdx.x;
    const int lane = t & 63, wv = t >> 6;
    const int wm = (wv >> 1) * 32, wn = (wv & 1) * 64;
    const int lr = lane & 15, lg = lane >> 4;
    const int srow = lane >> 2, scol = (lane & 3) << 3;

    if (MODE == 1) {
        // inline squash stats from GEMM1's partial row sums (no extra dispatch)
        if (t < 192) {
            int r = (t < 64) ? (bm + t) : (bn + (t - 64));
            float tot = 0.f;
#pragma unroll
            for (int c = 0; c < NPART; c++) tot += g.rowsqP[(size_t)c * N_TOT + r];
            float norm = sqrtf(tot + 1e-6f);
            float sg = 1.f / (1.f + __expf(-norm));
            float sc = sg / norm;
            float a = 0.5f * tot * sc * sc;
            if (t < 64) { sclM[t] = sc; ahM[t] = a; }
            else        { sclN[t - 64] = sc; ahN[t - 64] = a; }
        }
    }

    f32x4 acc[2][4];
#pragma unroll
    for (int i = 0; i < 2; i++)
#pragma unroll
        for (int j = 0; j < 4; j++) acc[i][j] = (f32x4){0.f, 0.f, 0.f, 0.f};

    const unsigned short* Abase = g.A + (size_t)(bm + wv * 16 + srow) * g.lda + scol;
    const unsigned short* Bbase = g.B + (size_t)(bn + wv * 32 + srow) * g.ldb + scol;
    const size_t b16 = (size_t)16 * g.ldb;

    auto STAGE = [&](int kk, int buf) {
        stage16(Abase + kk,       &As[buf][wv * 16][0]);
        stage16(Bbase + kk,       &Bs[buf][wv * 32][0]);
        stage16(Bbase + kk + b16, &Bs[buf][wv * 32 + 16][0]);
    };
    auto COMPUTE = [&](int buf) {
        bf16x8 af[2], bf[4];
#pragma unroll
        for (int i = 0; i < 2; i++)
            af[i] = *(const bf16x8*)&As[buf][wm + i * 16 + lr][lg * 8];
#pragma unroll
        for (int j = 0; j < 4; j++)
            bf[j] = *(const bf16x8*)&Bs[buf][wn + j * 16 + lr][lg * 8];
#pragma unroll
        for (int i = 0; i < 2; i++)
#pragma unroll
            for (int j = 0; j < 4; j++)
                acc[i][j] = __builtin_amdgcn_mfma_f32_16x16x32_bf16(af[i], bf[j], acc[i][j], 0, 0, 0);
    };

    const int nt = g.K >> 5;
    STAGE(0, 0);
    asm volatile("s_waitcnt vmcnt(0) lgkmcnt(0)" ::: "memory");
    __builtin_amdgcn_s_barrier();
    __builtin_amdgcn_sched_barrier(0);
    int cur = 0;
    for (int tt = 0; tt < nt - 1; ++tt) {
        STAGE((tt + 1) << 5, cur ^ 1);
        COMPUTE(cur);
        asm volatile("s_waitcnt vmcnt(0)" ::: "memory");
        __builtin_amdgcn_s_barrier();
        __builtin_amdgcn_sched_barrier(0);
        cur ^= 1;
    }
    COMPUTE(cur);

    // ---------------- epilogues ----------------
    if (MODE == 0) {
#pragma unroll
        for (int i = 0; i < 2; i++) {
#pragma unroll
            for (int reg = 0; reg < 4; reg++) {
                int m = bm + wm + i * 16 + lg * 4 + reg;
                float sq = 0.f;
#pragma unroll
                for (int j = 0; j < 4; j++) {
                    int n = bn + wn + j * 16 + lr;
                    float v = acc[i][j][reg];
                    if (n < D_DIM) v += g.psi[(size_t)m * D_DIM + n];
                    else v = 0.f;
                    if (n < D_PAD) g.u16[(size_t)m * D_PAD + n] = f2bf(v);
                    sq += v * v;
                }
                sq += __shfl_xor(sq, 1);
                sq += __shfl_xor(sq, 2);
                sq += __shfl_xor(sq, 4);
                sq += __shfl_xor(sq, 8);
                if (lr == 0)
                    g.rowsqP[(size_t)(blockIdx.x * 2 + (wn >> 6)) * N_TOT + m] = sq;
            }
        }
    } else if (MODE == 1) {
        __syncthreads();  // ensure stats visible (redundant with K-loop barriers, cheap)
#pragma unroll
        for (int i = 0; i < 2; i++) {
#pragma unroll
            for (int reg = 0; reg < 4; reg++) {
                int mi = wm + i * 16 + lg * 4 + reg;
                int m = bm + mi;
                float sm = sclM[mi], am = ahM[mi];
#pragma unroll
                for (int j = 0; j < 4; j++) {
                    int ni = wn + j * 16 + lr;
                    int n = bn + ni;
                    float uv = acc[i][j][reg] * sm * sclN[ni];
                    float kv = __expf(uv - am - ahN[ni]) * uv;
                    size_t idx = (size_t)m * S_ANCH + n;
                    if (!g.finish) {
                        if (g.first) g.accb[idx] = kv;
                        else g.accb[idx] += 2.0f * kv;
                        float zt = g.zcur[idx] + g.alpha * kv;
                        g.zt16[idx] = f2bf(zt);
                    } else {
                        float z = g.zcur[idx] + g.h6 * (g.accb[idx] + kv);
                        g.zcur[idx] = z;
                        g.zt16[idx] = f2bf(z);
                        if (m >= S_ANCH)
                            g.outp[(size_t)(m - S_ANCH) * (F_NUM * S_ANCH)
                                   + (size_t)g.tout * S_ANCH + n] = z;
                    }
                }
            }
        }
    } else {
        float s = 0.f;
#pragma unroll
        for (int i = 0; i < 2; i++)
#pragma unroll
            for (int reg = 0; reg < 4; reg++) {
                int m = bm + wm + i * 16 + lg * 4 + reg;
#pragma unroll
                for (int j = 0; j < 4; j++) {
                    int n = bn + wn + j * 16 + lr;
                    if (n < D_DIM) s += acc[i][j][reg] * g.cfp[(size_t)m * D_DIM + n];
                }
            }
        s += __shfl_xor(s, 1); s += __shfl_xor(s, 2); s += __shfl_xor(s, 4);
        s += __shfl_xor(s, 8); s += __shfl_xor(s, 16); s += __shfl_xor(s, 32);
        if (lane == 0) red4[wv] = s;
        __syncthreads();
        if (t == 0) atomicAdd(g.cost, red4[0] + red4[1] + red4[2] + red4[3]);
    }
}

// ---------------- final: add conv_w/b square norm ----------------
__global__ __launch_bounds__(256) void final_kernel(const float* __restrict__ cw,
                                                    const float* __restrict__ cb,
                                                    const float* __restrict__ cost,
                                                    float* __restrict__ out) {
    float s = 0.f;
    for (int i = threadIdx.x; i < 720; i += 256) s += cw[i] * cw[i];
    for (int i = threadIdx.x; i < 80; i += 256) s += cb[i] * cb[i];
    for (int o = 32; o > 0; o >>= 1) s += __shfl_down(s, o);
    __shared__ float red[4];
    if ((threadIdx.x & 63) == 0) red[threadIdx.x >> 6] = s;
    __syncthreads();
    if (threadIdx.x == 0) out[0] = red[0] + red[1] + red[2] + red[3] + cost[0] / 10.0f;
}

// ---------------- host ----------------
extern "C" void kernel_launch(void* const* d_in, const int* in_sizes, int n_in,
                              void* d_out, int out_size, void* d_ws, size_t ws_size,
                              hipStream_t stream) {
    (void)in_sizes; (void)n_in; (void)out_size; (void)ws_size;
    const float* data   = (const float*)d_in[0];
    const float* inputs = (const float*)d_in[1];
    const float* conv_w = (const float*)d_in[2];
    const float* conv_b = (const float*)d_in[3];
    const float* c_s    = (const float*)d_in[4];
    float* out = (float*)d_out;

    char* ws = (char*)d_ws;
    size_t off = 0;
    auto alloc = [&](size_t bytes) {
        char* p = ws + off; off += (bytes + 255) & ~(size_t)255; return p;
    };
    float*          c_buf  = (float*)alloc(SD * 4);
    unsigned short* c16T   = (unsigned short*)alloc((size_t)D_BPAD * S_ANCH * 2);
    float*          psi    = (float*)alloc(ND * 4);
    unsigned short* u16    = (unsigned short*)alloc((size_t)N_TOT * D_PAD * 2);
    float*          z_cur  = (float*)alloc(NS * 4);
    unsigned short* z16    = (unsigned short*)alloc(NS * 2);
    unsigned short* zt16   = (unsigned short*)alloc(NS * 2);
    float*          accb   = (float*)alloc(NS * 4);
    float*          rowsqP = (float*)alloc((size_t)NPART * N_TOT * 4);
    float*          cost   = (float*)alloc(64);

    const double TAU_D = 6.2831853071795864769;
    float ts[F_NUM];
    for (int i = 0; i < F_NUM; i++) ts[i] = (float)((double)i / 9.0);
    float Wt[N_TV][F_NUM];
    for (int j = 0; j < N_TV; j++) {
        float tt;
        if ((j & 1) == 0) tt = ts[j >> 1];
        else {
            int i = j >> 1;
            float h = ts[i + 1] - ts[i];
            tt = ts[i] + 0.5f * h;
        }
        for (int f = 0; f < F_NUM; f++) {
            float coeff = (float)(TAU_D * f);
            float targ = tt * coeff;
            Wt[j][f] = (float)cos((double)targ);
        }
    }

    init_kernel<<<2048, 256, 0, stream>>>(z_cur, z16, cost, c16T, out);

    const int conv_blocks = (int)(((size_t)N_TOT * 8 * 169 + 255) / 256);

    GemmArgs g0 = {}; // GEMM1: u = z@cT + psi
    g0.B = c16T; g0.lda = S_ANCH; g0.ldb = S_ANCH; g0.K = S_ANCH;
    g0.psi = psi; g0.u16 = u16; g0.rowsqP = rowsqP;
    GemmArgs g1 = {}; // GEMM2: kernel + RK4 bookkeeping
    g1.A = u16; g1.B = u16; g1.lda = D_PAD; g1.ldb = D_PAD; g1.K = D_PAD;
    g1.zcur = z_cur; g1.accb = accb; g1.rowsqP = rowsqP;
    GemmArgs g2 = {}; // cost quadratic form
    g2.A = z16; g2.B = c16T; g2.lda = S_ANCH; g2.ldb = S_ANCH; g2.K = S_ANCH;
    g2.cfp = c_buf; g2.cost = cost;

    int cur_j = -1;
    for (int i = 0; i < 9; i++) {
        float h = ts[i + 1] - ts[i];
        int js[4] = {2 * i, 2 * i + 1, 2 * i + 1, 2 * i + 2};
        float alphas[3] = {0.5f * h, 0.5f * h, h};
        for (int e = 0; e < 4; e++) {
            int j = js[e];
            if (j != cur_j) {
                W10 w;
                for (int f = 0; f < F_NUM; f++) w.w[f] = Wt[j][f];
                compute_c_kernel<<<dim3(22, 32), 256, 0, stream>>>(c_s, c_buf, c16T, w);
                conv_psi_kernel<<<conv_blocks, 256, 0, stream>>>(data, inputs, conv_w, conv_b, psi, w);
                cur_j = j;
            }
            g0.A = (e == 0) ? z16 : zt16;
            mfma_gemm<0><<<dim3(11, 48), 256, 0, stream>>>(g0);
            g1.first = (e == 0); g1.finish = (e == 3);
            g1.alpha = (e < 3) ? alphas[e] : 0.f;
            g1.h6 = h / 6.0f; g1.tout = i + 1;
            g1.zt16 = (e < 3) ? zt16 : z16;
            g1.outp = out;
            mfma_gemm<1><<<dim3(8, 48), 256, 0, stream>>>(g1);
        }
        mfma_gemm<2><<<dim3(11, 16), 256, 0, stream>>>(g2);
    }

    final_kernel<<<1, 256, 0, stream>>>(conv_w, conv_b, cost, out + OUT_Z);
}

// Round 5
// 3155.556 us; speedup vs baseline: 4.5738x; 1.1892x over previous
//
#include <hip/hip_runtime.h>
#include <math.h>

#define S_ANCH 1024
#define B_QRY  2048
#define N_TOT  3072
#define D_DIM  1352
#define D_PAD  1376   // K for GEMM2, multiple of 32
#define D_BPAD 1408   // c16T rows, multiple of 64
#define F_NUM  10
#define N_TV   19
#define NPART  44     // 22 n-tiles * 2 wave-halves in GEMM1

static const size_t ND = (size_t)N_TOT * D_DIM;
static const size_t SD = (size_t)S_ANCH * D_DIM;
static const size_t NS = (size_t)N_TOT * S_ANCH;
static const size_t OUT_Z = (size_t)B_QRY * F_NUM * S_ANCH;

typedef __attribute__((ext_vector_type(8))) short bf16x8;
typedef __attribute__((ext_vector_type(4))) float f32x4;

struct W10 { float w[F_NUM]; };

__device__ inline unsigned short f2bf(float x) {
    unsigned int u = __builtin_bit_cast(unsigned int, x);
    unsigned int r = (u + 0x7FFFu + ((u >> 16) & 1u)) >> 16;
    return (unsigned short)r;
}

__device__ __forceinline__ void stage16(const unsigned short* gp, unsigned short* lp) {
    __builtin_amdgcn_global_load_lds(
        (const __attribute__((address_space(1))) unsigned int*)(const void*)gp,
        (__attribute__((address_space(3))) unsigned int*)(void*)lp, 16, 0, 0);
}

// ---------------- init: zero z, z16, cost, c16T pad rows, t=0 out slice ----------------
__global__ __launch_bounds__(256) void init_kernel(float* __restrict__ z,
                                                   unsigned short* __restrict__ z16,
                                                   float* __restrict__ cost,
                                                   unsigned short* __restrict__ c16T,
                                                   float* __restrict__ out) {
    size_t idx = (size_t)blockIdx.x * blockDim.x + threadIdx.x;
    size_t stride = (size_t)gridDim.x * blockDim.x;
    for (size_t i = idx; i < NS; i += stride) { z[i] = 0.f; z16[i] = 0; }
    const size_t NO = (size_t)B_QRY * S_ANCH;
    for (size_t i = idx; i < NO; i += stride) {
        size_t b = i >> 10, s = i & 1023;
        out[b * (size_t)(F_NUM * S_ANCH) + s] = 0.f;
    }
    const size_t PADN = (size_t)(D_BPAD - D_DIM) * S_ANCH;
    for (size_t i = idx; i < PADN; i += stride)
        c16T[(size_t)D_DIM * S_ANCH + i] = 0;
    if (idx == 0) cost[0] = 0.f;
}

// ---------------- c_t: fp32 [S][D] + bf16 transposed [D_BPAD][S] ----------------
__global__ __launch_bounds__(256) void compute_c_kernel(const float* __restrict__ cs,
                                                        float* __restrict__ cfp,
                                                        unsigned short* __restrict__ c16T,
                                                        W10 W) {
    __shared__ float tile[32][65];
    int d0 = blockIdx.x * 64, s0 = blockIdx.y * 32;
    int t = threadIdx.x;
    int d_l = t & 63, s_l0 = t >> 6;
    for (int ss = s_l0; ss < 32; ss += 4) {
        int d = d0 + d_l, s = s0 + ss;
        float v = 0.f;
        if (d < D_DIM) {
            const float* p = cs + ((size_t)s * D_DIM + d) * F_NUM;
#pragma unroll
            for (int f = 0; f < F_NUM; f++) v += p[f] * W.w[f];
            cfp[(size_t)s * D_DIM + d] = v;
        }
        tile[ss][d_l] = v;
    }
    __syncthreads();
    int s_l = t & 31, d_l1 = t >> 5;
    for (int dd = d_l1; dd < 64; dd += 8) {
        int d = d0 + dd;
        if (d < D_DIM)
            c16T[(size_t)d * S_ANCH + s0 + s_l] = f2bf(tile[s_l][dd]);
    }
}

// ---------------- psi_t[n,d] : conv fused with freq dot (fp32) ----------------
__global__ __launch_bounds__(256) void conv_psi_kernel(const float* __restrict__ data,
                                                       const float* __restrict__ inputs,
                                                       const float* __restrict__ cw,
                                                       const float* __restrict__ cb,
                                                       float* __restrict__ psi, W10 W) {
    __shared__ float wsh[720];
    __shared__ float bsh[80];
    for (int i = threadIdx.x; i < 720; i += 256) wsh[i] = cw[i];
    for (int i = threadIdx.x; i < 80; i += 256) bsh[i] = cb[i];
    __syncthreads();
    size_t idx = (size_t)blockIdx.x * 256 + threadIdx.x;
    if (idx >= (size_t)N_TOT * 8 * 169) return;
    int pos = (int)(idx % 169);
    int rest = (int)(idx / 169);
    int c8 = rest & 7;
    int n = rest >> 3;
    int oi = pos / 13, oj = pos % 13;
    const float* x = (n < S_ANCH) ? (data + (size_t)n * 784)
                                  : (inputs + (size_t)(n - S_ANCH) * 784);
    float vin[9];
#pragma unroll
    for (int kh = 0; kh < 3; kh++)
#pragma unroll
        for (int kw = 0; kw < 3; kw++)
            vin[kh * 3 + kw] = x[(2 * oi + kh) * 28 + (2 * oj + kw)];
    float p = 0.f;
#pragma unroll
    for (int f = 0; f < F_NUM; f++) {
        int co = f * 8 + c8;
        float s = bsh[co];
#pragma unroll
        for (int t = 0; t < 9; t++) s += vin[t] * wsh[co * 9 + t];
        p += s * W.w[f];
    }
    psi[(size_t)n * D_DIM + c8 * 169 + pos] = p;
}

// ---------------- MFMA GEMM (NT), 64x64 tile, BK=32, 2-phase gload_lds ----------------
// 4 waves; wave (wv>>1, wv&1) owns a 32x32 sub-tile: acc[2][2].
struct GemmArgs {
    const unsigned short* A; const unsigned short* B;
    int lda, ldb, K;
    // MODE 0
    const float* psi; unsigned short* u16; float* rowsqP;
    // MODE 1
    float* zcur; float* accb; unsigned short* zt16; float* outp;
    int first, finish, tout; float alpha, h6;
    // MODE 2
    const float* cfp; float* cost;
};

template<int MODE>
__global__ __launch_bounds__(256) void mfma_gemm(GemmArgs g) {
    __shared__ __align__(16) unsigned short As[2][64][32];
    __shared__ __align__(16) unsigned short Bs[2][64][32];
    __shared__ float sclM[64], ahM[64], sclN[64], ahN[64];
    __shared__ float red4[4];
    const int bm = blockIdx.y * 64, bn = blockIdx.x * 64;
    const int t = threadIdx.x;
    const int lane = t & 63, wv = t >> 6;
    const int wm = (wv >> 1) * 32, wn = (wv & 1) * 32;
    const int lr = lane & 15, lg = lane >> 4;
    const int srow = lane >> 2, scol = (lane & 3) << 3;

    if (MODE == 1) {
        // inline squash stats from GEMM1's partial row sums (no extra dispatch)
        if (t < 128) {
            int r = (t < 64) ? (bm + t) : (bn + (t - 64));
            float tot = 0.f;
#pragma unroll
            for (int c = 0; c < NPART; c++) tot += g.rowsqP[(size_t)c * N_TOT + r];
            float norm = sqrtf(tot + 1e-6f);
            float sg = 1.f / (1.f + __expf(-norm));
            float sc = sg / norm;
            float a = 0.5f * tot * sc * sc;
            if (t < 64) { sclM[t] = sc; ahM[t] = a; }
            else        { sclN[t - 64] = sc; ahN[t - 64] = a; }
        }
    }

    f32x4 acc[2][2];
#pragma unroll
    for (int i = 0; i < 2; i++)
#pragma unroll
        for (int j = 0; j < 2; j++) acc[i][j] = (f32x4){0.f, 0.f, 0.f, 0.f};

    const unsigned short* Abase = g.A + (size_t)(bm + wv * 16 + srow) * g.lda + scol;
    const unsigned short* Bbase = g.B + (size_t)(bn + wv * 16 + srow) * g.ldb + scol;

    auto STAGE = [&](int kk, int buf) {
        stage16(Abase + kk, &As[buf][wv * 16][0]);
        stage16(Bbase + kk, &Bs[buf][wv * 16][0]);
    };
    auto COMPUTE = [&](int buf) {
        bf16x8 af[2], bf[2];
#pragma unroll
        for (int i = 0; i < 2; i++)
            af[i] = *(const bf16x8*)&As[buf][wm + i * 16 + lr][lg * 8];
#pragma unroll
        for (int j = 0; j < 2; j++)
            bf[j] = *(const bf16x8*)&Bs[buf][wn + j * 16 + lr][lg * 8];
#pragma unroll
        for (int i = 0; i < 2; i++)
#pragma unroll
            for (int j = 0; j < 2; j++)
                acc[i][j] = __builtin_amdgcn_mfma_f32_16x16x32_bf16(af[i], bf[j], acc[i][j], 0, 0, 0);
    };

    const int nt = g.K >> 5;
    STAGE(0, 0);
    asm volatile("s_waitcnt vmcnt(0) lgkmcnt(0)" ::: "memory");
    __builtin_amdgcn_s_barrier();
    __builtin_amdgcn_sched_barrier(0);
    int cur = 0;
    for (int tt = 0; tt < nt - 1; ++tt) {
        STAGE((tt + 1) << 5, cur ^ 1);
        COMPUTE(cur);
        asm volatile("s_waitcnt vmcnt(0)" ::: "memory");
        __builtin_amdgcn_s_barrier();
        __builtin_amdgcn_sched_barrier(0);
        cur ^= 1;
    }
    COMPUTE(cur);

    // ---------------- epilogues ----------------
    if (MODE == 0) {
#pragma unroll
        for (int i = 0; i < 2; i++) {
#pragma unroll
            for (int reg = 0; reg < 4; reg++) {
                int m = bm + wm + i * 16 + lg * 4 + reg;
                float sq = 0.f;
#pragma unroll
                for (int j = 0; j < 2; j++) {
                    int n = bn + wn + j * 16 + lr;
                    float v = acc[i][j][reg];
                    if (n < D_DIM) v += g.psi[(size_t)m * D_DIM + n];
                    else v = 0.f;
                    if (n < D_PAD) g.u16[(size_t)m * D_PAD + n] = f2bf(v);
                    sq += v * v;
                }
                sq += __shfl_xor(sq, 1);
                sq += __shfl_xor(sq, 2);
                sq += __shfl_xor(sq, 4);
                sq += __shfl_xor(sq, 8);
                if (lr == 0)
                    g.rowsqP[(size_t)(blockIdx.x * 2 + (wn >> 5)) * N_TOT + m] = sq;
            }
        }
    } else if (MODE == 1) {
        __syncthreads();  // stats visibility (ordered by K-loop barriers; keep for safety)
#pragma unroll
        for (int i = 0; i < 2; i++) {
#pragma unroll
            for (int reg = 0; reg < 4; reg++) {
                int mi = wm + i * 16 + lg * 4 + reg;
                int m = bm + mi;
                float sm = sclM[mi], am = ahM[mi];
#pragma unroll
                for (int j = 0; j < 2; j++) {
                    int ni = wn + j * 16 + lr;
                    int n = bn + ni;
                    float uv = acc[i][j][reg] * sm * sclN[ni];
                    float kv = __expf(uv - am - ahN[ni]) * uv;
                    size_t idx = (size_t)m * S_ANCH + n;
                    if (!g.finish) {
                        if (g.first) g.accb[idx] = kv;
                        else g.accb[idx] += 2.0f * kv;
                        float zt = g.zcur[idx] + g.alpha * kv;
                        g.zt16[idx] = f2bf(zt);
                    } else {
                        float z = g.zcur[idx] + g.h6 * (g.accb[idx] + kv);
                        g.zcur[idx] = z;
                        g.zt16[idx] = f2bf(z);
                        if (m >= S_ANCH)
                            g.outp[(size_t)(m - S_ANCH) * (F_NUM * S_ANCH)
                                   + (size_t)g.tout * S_ANCH + n] = z;
                    }
                }
            }
        }
    } else {
        float s = 0.f;
#pragma unroll
        for (int i = 0; i < 2; i++)
#pragma unroll
            for (int reg = 0; reg < 4; reg++) {
                int m = bm + wm + i * 16 + lg * 4 + reg;
#pragma unroll
                for (int j = 0; j < 2; j++) {
                    int n = bn + wn + j * 16 + lr;
                    if (n < D_DIM) s += acc[i][j][reg] * g.cfp[(size_t)m * D_DIM + n];
                }
            }
        s += __shfl_xor(s, 1); s += __shfl_xor(s, 2); s += __shfl_xor(s, 4);
        s += __shfl_xor(s, 8); s += __shfl_xor(s, 16); s += __shfl_xor(s, 32);
        if (lane == 0) red4[wv] = s;
        __syncthreads();
        if (t == 0) atomicAdd(g.cost, red4[0] + red4[1] + red4[2] + red4[3]);
    }
}

// ---------------- final: add conv_w/b square norm ----------------
__global__ __launch_bounds__(256) void final_kernel(const float* __restrict__ cw,
                                                    const float* __restrict__ cb,
                                                    const float* __restrict__ cost,
                                                    float* __restrict__ out) {
    float s = 0.f;
    for (int i = threadIdx.x; i < 720; i += 256) s += cw[i] * cw[i];
    for (int i = threadIdx.x; i < 80; i += 256) s += cb[i] * cb[i];
    for (int o = 32; o > 0; o >>= 1) s += __shfl_down(s, o);
    __shared__ float red[4];
    if ((threadIdx.x & 63) == 0) red[threadIdx.x >> 6] = s;
    __syncthreads();
    if (threadIdx.x == 0) out[0] = red[0] + red[1] + red[2] + red[3] + cost[0] / 10.0f;
}

// ---------------- host ----------------
extern "C" void kernel_launch(void* const* d_in, const int* in_sizes, int n_in,
                              void* d_out, int out_size, void* d_ws, size_t ws_size,
                              hipStream_t stream) {
    (void)in_sizes; (void)n_in; (void)out_size; (void)ws_size;
    const float* data   = (const float*)d_in[0];
    const float* inputs = (const float*)d_in[1];
    const float* conv_w = (const float*)d_in[2];
    const float* conv_b = (const float*)d_in[3];
    const float* c_s    = (const float*)d_in[4];
    float* out = (float*)d_out;

    char* ws = (char*)d_ws;
    size_t off = 0;
    auto alloc = [&](size_t bytes) {
        char* p = ws + off; off += (bytes + 255) & ~(size_t)255; return p;
    };
    float*          c_buf  = (float*)alloc(SD * 4);
    unsigned short* c16T   = (unsigned short*)alloc((size_t)D_BPAD * S_ANCH * 2);
    float*          psi    = (float*)alloc(ND * 4);
    unsigned short* u16    = (unsigned short*)alloc((size_t)N_TOT * D_PAD * 2);
    float*          z_cur  = (float*)alloc(NS * 4);
    unsigned short* z16    = (unsigned short*)alloc(NS * 2);
    unsigned short* zt16   = (unsigned short*)alloc(NS * 2);
    float*          accb   = (float*)alloc(NS * 4);
    float*          rowsqP = (float*)alloc((size_t)NPART * N_TOT * 4);
    float*          cost   = (float*)alloc(64);

    const double TAU_D = 6.2831853071795864769;
    float ts[F_NUM];
    for (int i = 0; i < F_NUM; i++) ts[i] = (float)((double)i / 9.0);
    float Wt[N_TV][F_NUM];
    for (int j = 0; j < N_TV; j++) {
        float tt;
        if ((j & 1) == 0) tt = ts[j >> 1];
        else {
            int i = j >> 1;
            float h = ts[i + 1] - ts[i];
            tt = ts[i] + 0.5f * h;
        }
        for (int f = 0; f < F_NUM; f++) {
            float coeff = (float)(TAU_D * f);
            float targ = tt * coeff;
            Wt[j][f] = (float)cos((double)targ);
        }
    }

    init_kernel<<<2048, 256, 0, stream>>>(z_cur, z16, cost, c16T, out);

    const int conv_blocks = (int)(((size_t)N_TOT * 8 * 169 + 255) / 256);

    GemmArgs g0 = {}; // GEMM1: u = z@cT + psi
    g0.B = c16T; g0.lda = S_ANCH; g0.ldb = S_ANCH; g0.K = S_ANCH;
    g0.psi = psi; g0.u16 = u16; g0.rowsqP = rowsqP;
    GemmArgs g1 = {}; // GEMM2: kernel + RK4 bookkeeping
    g1.A = u16; g1.B = u16; g1.lda = D_PAD; g1.ldb = D_PAD; g1.K = D_PAD;
    g1.zcur = z_cur; g1.accb = accb; g1.rowsqP = rowsqP;
    GemmArgs g2 = {}; // cost quadratic form
    g2.A = z16; g2.B = c16T; g2.lda = S_ANCH; g2.ldb = S_ANCH; g2.K = S_ANCH;
    g2.cfp = c_buf; g2.cost = cost;

    int cur_j = -1;
    for (int i = 0; i < 9; i++) {
        float h = ts[i + 1] - ts[i];
        int js[4] = {2 * i, 2 * i + 1, 2 * i + 1, 2 * i + 2};
        float alphas[3] = {0.5f * h, 0.5f * h, h};
        for (int e = 0; e < 4; e++) {
            int j = js[e];
            if (j != cur_j) {
                W10 w;
                for (int f = 0; f < F_NUM; f++) w.w[f] = Wt[j][f];
                compute_c_kernel<<<dim3(22, 32), 256, 0, stream>>>(c_s, c_buf, c16T, w);
                conv_psi_kernel<<<conv_blocks, 256, 0, stream>>>(data, inputs, conv_w, conv_b, psi, w);
                cur_j = j;
            }
            g0.A = (e == 0) ? z16 : zt16;
            mfma_gemm<0><<<dim3(22, 48), 256, 0, stream>>>(g0);
            g1.first = (e == 0); g1.finish = (e == 3);
            g1.alpha = (e < 3) ? alphas[e] : 0.f;
            g1.h6 = h / 6.0f; g1.tout = i + 1;
            g1.zt16 = (e < 3) ? zt16 : z16;
            g1.outp = out;
            mfma_gemm<1><<<dim3(16, 48), 256, 0, stream>>>(g1);
        }
        mfma_gemm<2><<<dim3(22, 16), 256, 0, stream>>>(g2);
    }

    final_kernel<<<1, 256, 0, stream>>>(conv_w, conv_b, cost, out + OUT_Z);
}

// Round 6
// 2799.646 us; speedup vs baseline: 5.1553x; 1.1271x over previous
//
#include <hip/hip_runtime.h>
#include <math.h>

#define S_ANCH 1024
#define B_QRY  2048
#define N_TOT  3072
#define D_DIM  1352
#define D_PAD  1408   // padded D: u16 stride, GEMM2 K, c16T rows (22*64)
#define F_NUM  10
#define N_TV   19
#define NPART  44     // 22 n-tiles * 2 wave-halves in GEMM1

static const size_t SD    = (size_t)S_ANCH * D_DIM;
static const size_t NS    = (size_t)N_TOT * S_ANCH;
static const size_t CST   = (size_t)D_PAD * S_ANCH;  // one c16T plane
static const size_t OUT_Z = (size_t)B_QRY * F_NUM * S_ANCH;

typedef __attribute__((ext_vector_type(8))) short bf16x8;
typedef __attribute__((ext_vector_type(4))) float f32x4;

struct W10  { float w[F_NUM]; };
struct W190 { float w[N_TV][F_NUM]; };

__device__ inline unsigned short f2bf(float x) {
    unsigned int u = __builtin_bit_cast(unsigned int, x);
    unsigned int r = (u + 0x7FFFu + ((u >> 16) & 1u)) >> 16;
    return (unsigned short)r;
}
__device__ inline float bf2f(unsigned short v) {
    unsigned int u = ((unsigned int)v) << 16;
    return __builtin_bit_cast(float, u);
}

__device__ __forceinline__ void stage16(const unsigned short* gp, unsigned short* lp) {
    __builtin_amdgcn_global_load_lds(
        (const __attribute__((address_space(1))) unsigned int*)(const void*)gp,
        (__attribute__((address_space(3))) unsigned int*)(void*)lp, 16, 0, 0);
}

// ---------------- init: zero z, z16, cost, t=0 out slice ----------------
__global__ __launch_bounds__(256) void init_kernel(float* __restrict__ z,
                                                   unsigned short* __restrict__ z16,
                                                   float* __restrict__ cost,
                                                   float* __restrict__ out) {
    size_t idx = (size_t)blockIdx.x * blockDim.x + threadIdx.x;
    size_t stride = (size_t)gridDim.x * blockDim.x;
    for (size_t i = idx; i < NS; i += stride) { z[i] = 0.f; z16[i] = 0; }
    const size_t NO = (size_t)B_QRY * S_ANCH;
    for (size_t i = idx; i < NO; i += stride) {
        size_t b = i >> 10, s = i & 1023;
        out[b * (size_t)(F_NUM * S_ANCH) + s] = 0.f;
    }
    if (idx == 0) cost[0] = 0.f;
}

// ---------------- ALL c_t planes in one pass over c_s ----------------
// c16T_all[j][d][s] bf16 (d<D_PAD, zero-padded), cfp_all[gi][s][d] fp32 for grid
// times t_1..t_9 (j=2,4,..,18). grid (22, 32), block 256.
__global__ __launch_bounds__(256) void c_all_kernel(const float* __restrict__ cs,
                                                    unsigned short* __restrict__ cT,
                                                    float* __restrict__ cfp, W190 W) {
    __shared__ float tile[32][65];
    int d0 = blockIdx.x * 64, s0 = blockIdx.y * 32;
    int t = threadIdx.x;
    int d_l = t & 63, s_base = t >> 6;
    int d = d0 + d_l;
    bool dok = (d < D_DIM);
    float creg[8][F_NUM];
#pragma unroll
    for (int it = 0; it < 8; it++) {
        int s = s0 + s_base + it * 4;
        const float* p = cs + ((size_t)s * D_DIM + d) * F_NUM;
#pragma unroll
        for (int f = 0; f < F_NUM; f++) creg[it][f] = dok ? p[f] : 0.f;
    }
    for (int j = 0; j < N_TV; j++) {
        float v[8];
#pragma unroll
        for (int it = 0; it < 8; it++) {
            float s = 0.f;
#pragma unroll
            for (int f = 0; f < F_NUM; f++) s += creg[it][f] * W.w[j][f];
            v[it] = s;
            tile[s_base + it * 4][d_l] = s;
        }
        if ((j & 1) == 0 && j >= 2 && dok) {
            int gi = (j >> 1) - 1;
#pragma unroll
            for (int it = 0; it < 8; it++)
                cfp[(size_t)gi * SD + (size_t)(s0 + s_base + it * 4) * D_DIM + d] = v[it];
        }
        __syncthreads();
        int s_l = t & 31, dr = t >> 5;
#pragma unroll
        for (int p8 = 0; p8 < 8; p8++) {
            int dd = dr + p8 * 8;
            cT[(size_t)j * CST + (size_t)(d0 + dd) * S_ANCH + s0 + s_l] = f2bf(tile[s_l][dd]);
        }
        __syncthreads();
    }
}

// ---------------- psi_t[n,d] : conv fused with freq dot -> bf16 ----------------
__global__ __launch_bounds__(256) void conv_psi_kernel(const float* __restrict__ data,
                                                       const float* __restrict__ inputs,
                                                       const float* __restrict__ cw,
                                                       const float* __restrict__ cb,
                                                       unsigned short* __restrict__ psi16,
                                                       W10 W) {
    __shared__ float wsh[720];
    __shared__ float bsh[80];
    for (int i = threadIdx.x; i < 720; i += 256) wsh[i] = cw[i];
    for (int i = threadIdx.x; i < 80; i += 256) bsh[i] = cb[i];
    __syncthreads();
    size_t idx = (size_t)blockIdx.x * 256 + threadIdx.x;
    if (idx >= (size_t)N_TOT * 8 * 169) return;
    int pos = (int)(idx % 169);
    int rest = (int)(idx / 169);
    int c8 = rest & 7;
    int n = rest >> 3;
    int oi = pos / 13, oj = pos % 13;
    const float* x = (n < S_ANCH) ? (data + (size_t)n * 784)
                                  : (inputs + (size_t)(n - S_ANCH) * 784);
    float vin[9];
#pragma unroll
    for (int kh = 0; kh < 3; kh++)
#pragma unroll
        for (int kw = 0; kw < 3; kw++)
            vin[kh * 3 + kw] = x[(2 * oi + kh) * 28 + (2 * oj + kw)];
    float p = 0.f;
#pragma unroll
    for (int f = 0; f < F_NUM; f++) {
        int co = f * 8 + c8;
        float s = bsh[co];
#pragma unroll
        for (int t = 0; t < 9; t++) s += vin[t] * wsh[co * 9 + t];
        p += s * W.w[f];
    }
    psi16[(size_t)n * D_PAD + c8 * 169 + pos] = f2bf(p);
}

// ---------------- MFMA GEMM (NT), 64x64 tile, BK=64, swizzled LDS ----------------
struct GemmArgs {
    const unsigned short* A; const unsigned short* B;
    int lda, ldb, K, gx;
    // MODE 0
    const unsigned short* psi16; unsigned short* u16; float* rowsqP;
    int do_cost;
    // MODE 0 (cost fusion) + MODE 2
    const float* cfp; float* cost;
    // MODE 1
    float* zcur; unsigned short* accb16; unsigned short* zt16; float* outp;
    int first, finish, tout; float alpha, h6;
};

template<int MODE>
__global__ __launch_bounds__(256) void mfma_gemm(GemmArgs g) {
    __shared__ __align__(16) unsigned short As[2][64][64];
    __shared__ __align__(16) unsigned short Bs[2][64][64];
    __shared__ float sclM[64], ahM[64], sclN[64], ahN[64];
    __shared__ float red4[4];
    // XCD-aware swizzle (all grids are multiples of 8)
    const int nb = gridDim.x;
    const int lin = blockIdx.x;
    const int swz = (lin & 7) * (nb >> 3) + (lin >> 3);
    const int bx = swz % g.gx, by = swz / g.gx;
    const int bm = by * 64, bn = bx * 64;
    const int t = threadIdx.x;
    const int lane = t & 63, wv = t >> 6;
    const int wm = (wv >> 1) * 32, wn = (wv & 1) * 32;
    const int lr = lane & 15, lg = lane >> 4;

    if (MODE == 1) {
        if (t < 128) {
            int r = (t < 64) ? (bm + t) : (bn + (t - 64));
            float tot = 0.f;
#pragma unroll
            for (int c = 0; c < NPART; c++) tot += g.rowsqP[(size_t)c * N_TOT + r];
            float norm = sqrtf(tot + 1e-6f);
            float sg = 1.f / (1.f + __expf(-norm));
            float sc = sg / norm;
            float a = 0.5f * tot * sc * sc;
            if (t < 64) { sclM[t] = sc; ahM[t] = a; }
            else        { sclN[t - 64] = sc; ahN[t - 64] = a; }
        }
    }

    f32x4 acc[2][2];
#pragma unroll
    for (int i = 0; i < 2; i++)
#pragma unroll
        for (int j = 0; j < 2; j++) acc[i][j] = (f32x4){0.f, 0.f, 0.f, 0.f};

    // staging: 2 calls per matrix per thread; linear LDS dest, swizzled source.
    const int rsub = lane >> 3;              // 0..7
    const int gch  = (lane & 7) ^ rsub;      // inverse-swizzled source chunk
    const int r0 = wv * 16 + rsub;
    const int r1 = wv * 16 + 8 + rsub;
    const unsigned short* A0 = g.A + (size_t)(bm + r0) * g.lda + gch * 8;
    const unsigned short* A1 = g.A + (size_t)(bm + r1) * g.lda + gch * 8;
    const unsigned short* B0 = g.B + (size_t)(bn + r0) * g.ldb + gch * 8;
    const unsigned short* B1 = g.B + (size_t)(bn + r1) * g.ldb + gch * 8;

    auto STAGE = [&](int kk, int buf) {
        stage16(A0 + kk, &As[buf][wv * 16][0]);
        stage16(A1 + kk, &As[buf][wv * 16 + 8][0]);
        stage16(B0 + kk, &Bs[buf][wv * 16][0]);
        stage16(B1 + kk, &Bs[buf][wv * 16 + 8][0]);
    };
    auto COMPUTE = [&](int buf) {
#pragma unroll
        for (int kc = 0; kc < 2; kc++) {
            const int sl = (kc * 4 + lg) ^ (lr & 7);  // swizzled read slot
            bf16x8 af[2], bf[2];
#pragma unroll
            for (int i = 0; i < 2; i++)
                af[i] = *(const bf16x8*)&As[buf][wm + i * 16 + lr][sl * 8];
#pragma unroll
            for (int j = 0; j < 2; j++)
                bf[j] = *(const bf16x8*)&Bs[buf][wn + j * 16 + lr][sl * 8];
#pragma unroll
            for (int i = 0; i < 2; i++)
#pragma unroll
                for (int j = 0; j < 2; j++)
                    acc[i][j] = __builtin_amdgcn_mfma_f32_16x16x32_bf16(af[i], bf[j], acc[i][j], 0, 0, 0);
        }
    };

    const int nt = g.K >> 6;
    STAGE(0, 0);
    asm volatile("s_waitcnt vmcnt(0) lgkmcnt(0)" ::: "memory");
    __builtin_amdgcn_s_barrier();
    __builtin_amdgcn_sched_barrier(0);
    int cur = 0;
    for (int tt = 0; tt < nt - 1; ++tt) {
        STAGE((tt + 1) << 6, cur ^ 1);
        COMPUTE(cur);
        asm volatile("s_waitcnt vmcnt(0)" ::: "memory");
        __builtin_amdgcn_s_barrier();
        __builtin_amdgcn_sched_barrier(0);
        cur ^= 1;
    }
    COMPUTE(cur);

    // ---------------- epilogues ----------------
    if (MODE == 0) {
        const bool docost = g.do_cost && (bm < S_ANCH);
        float cst = 0.f;
#pragma unroll
        for (int i = 0; i < 2; i++) {
#pragma unroll
            for (int reg = 0; reg < 4; reg++) {
                int m = bm + wm + i * 16 + lg * 4 + reg;
                float sq = 0.f;
#pragma unroll
                for (int j = 0; j < 2; j++) {
                    int n = bn + wn + j * 16 + lr;
                    float v = acc[i][j][reg];
                    bool nok = n < D_DIM;
                    if (docost && nok) cst += v * g.cfp[(size_t)m * D_DIM + n];
                    if (nok) v += bf2f(g.psi16[(size_t)m * D_PAD + n]);
                    else v = 0.f;
                    g.u16[(size_t)m * D_PAD + n] = f2bf(v);
                    sq += v * v;
                }
                sq += __shfl_xor(sq, 1);
                sq += __shfl_xor(sq, 2);
                sq += __shfl_xor(sq, 4);
                sq += __shfl_xor(sq, 8);
                if (lr == 0)
                    g.rowsqP[(size_t)(bx * 2 + (wn >> 5)) * N_TOT + m] = sq;
            }
        }
        if (docost) {
            cst += __shfl_xor(cst, 1); cst += __shfl_xor(cst, 2);
            cst += __shfl_xor(cst, 4); cst += __shfl_xor(cst, 8);
            cst += __shfl_xor(cst, 16); cst += __shfl_xor(cst, 32);
            if (lane == 0) red4[wv] = cst;
            __syncthreads();
            if (t == 0) atomicAdd(g.cost, red4[0] + red4[1] + red4[2] + red4[3]);
        }
    } else if (MODE == 1) {
        __syncthreads();  // stats visibility
#pragma unroll
        for (int i = 0; i < 2; i++) {
#pragma unroll
            for (int reg = 0; reg < 4; reg++) {
                int mi = wm + i * 16 + lg * 4 + reg;
                int m = bm + mi;
                float sm = sclM[mi], am = ahM[mi];
#pragma unroll
                for (int j = 0; j < 2; j++) {
                    int ni = wn + j * 16 + lr;
                    int n = bn + ni;
                    float uv = acc[i][j][reg] * sm * sclN[ni];
                    float kv = __expf(uv - am - ahN[ni]) * uv;
                    size_t idx = (size_t)m * S_ANCH + n;
                    if (!g.finish) {
                        float ab = g.first ? kv : (bf2f(g.accb16[idx]) + 2.0f * kv);
                        g.accb16[idx] = f2bf(ab);
                        float zt = g.zcur[idx] + g.alpha * kv;
                        g.zt16[idx] = f2bf(zt);
                    } else {
                        float z = g.zcur[idx] + g.h6 * (bf2f(g.accb16[idx]) + kv);
                        g.zcur[idx] = z;
                        g.zt16[idx] = f2bf(z);
                        if (m >= S_ANCH)
                            g.outp[(size_t)(m - S_ANCH) * (F_NUM * S_ANCH)
                                   + (size_t)g.tout * S_ANCH + n] = z;
                    }
                }
            }
        }
    } else {
        float s = 0.f;
#pragma unroll
        for (int i = 0; i < 2; i++)
#pragma unroll
            for (int reg = 0; reg < 4; reg++) {
                int m = bm + wm + i * 16 + lg * 4 + reg;
#pragma unroll
                for (int j = 0; j < 2; j++) {
                    int n = bn + wn + j * 16 + lr;
                    if (n < D_DIM) s += acc[i][j][reg] * g.cfp[(size_t)m * D_DIM + n];
                }
            }
        s += __shfl_xor(s, 1); s += __shfl_xor(s, 2); s += __shfl_xor(s, 4);
        s += __shfl_xor(s, 8); s += __shfl_xor(s, 16); s += __shfl_xor(s, 32);
        if (lane == 0) red4[wv] = s;
        __syncthreads();
        if (t == 0) atomicAdd(g.cost, red4[0] + red4[1] + red4[2] + red4[3]);
    }
}

// ---------------- final: add conv_w/b square norm ----------------
__global__ __launch_bounds__(256) void final_kernel(const float* __restrict__ cw,
                                                    const float* __restrict__ cb,
                                                    const float* __restrict__ cost,
                                                    float* __restrict__ out) {
    float s = 0.f;
    for (int i = threadIdx.x; i < 720; i += 256) s += cw[i] * cw[i];
    for (int i = threadIdx.x; i < 80; i += 256) s += cb[i] * cb[i];
    for (int o = 32; o > 0; o >>= 1) s += __shfl_down(s, o);
    __shared__ float red[4];
    if ((threadIdx.x & 63) == 0) red[threadIdx.x >> 6] = s;
    __syncthreads();
    if (threadIdx.x == 0) out[0] = red[0] + red[1] + red[2] + red[3] + cost[0] / 10.0f;
}

// ---------------- host ----------------
extern "C" void kernel_launch(void* const* d_in, const int* in_sizes, int n_in,
                              void* d_out, int out_size, void* d_ws, size_t ws_size,
                              hipStream_t stream) {
    (void)in_sizes; (void)n_in; (void)out_size; (void)ws_size;
    const float* data   = (const float*)d_in[0];
    const float* inputs = (const float*)d_in[1];
    const float* conv_w = (const float*)d_in[2];
    const float* conv_b = (const float*)d_in[3];
    const float* c_s    = (const float*)d_in[4];
    float* out = (float*)d_out;

    char* ws = (char*)d_ws;
    size_t off = 0;
    auto alloc = [&](size_t bytes) {
        char* p = ws + off; off += (bytes + 255) & ~(size_t)255; return p;
    };
    unsigned short* c16T_all = (unsigned short*)alloc((size_t)N_TV * CST * 2);  // 54.8 MB
    float*          cfp_all  = (float*)alloc((size_t)9 * SD * 4);               // 49.8 MB
    unsigned short* psi16    = (unsigned short*)alloc((size_t)N_TOT * D_PAD * 2);
    unsigned short* u16      = (unsigned short*)alloc((size_t)N_TOT * D_PAD * 2);
    float*          z_cur    = (float*)alloc(NS * 4);
    unsigned short* z16      = (unsigned short*)alloc(NS * 2);
    unsigned short* zt16     = (unsigned short*)alloc(NS * 2);
    unsigned short* accb16   = (unsigned short*)alloc(NS * 2);
    float*          rowsqP   = (float*)alloc((size_t)NPART * N_TOT * 4);
    float*          cost     = (float*)alloc(64);

    const double TAU_D = 6.2831853071795864769;
    float ts[F_NUM];
    for (int i = 0; i < F_NUM; i++) ts[i] = (float)((double)i / 9.0);
    W190 Wall;
    for (int j = 0; j < N_TV; j++) {
        float tt;
        if ((j & 1) == 0) tt = ts[j >> 1];
        else {
            int i = j >> 1;
            float h = ts[i + 1] - ts[i];
            tt = ts[i] + 0.5f * h;
        }
        for (int f = 0; f < F_NUM; f++) {
            float coeff = (float)(TAU_D * f);
            float targ = tt * coeff;
            Wall.w[j][f] = (float)cos((double)targ);
        }
    }

    init_kernel<<<2048, 256, 0, stream>>>(z_cur, z16, cost, out);
    c_all_kernel<<<dim3(22, 32), 256, 0, stream>>>(c_s, c16T_all, cfp_all, Wall);

    const int conv_blocks = (int)(((size_t)N_TOT * 8 * 169 + 255) / 256);

    GemmArgs g0 = {}; // GEMM1: u = z@cT + psi (+ fused cost at e=0)
    g0.lda = S_ANCH; g0.ldb = S_ANCH; g0.K = S_ANCH; g0.gx = 22;
    g0.psi16 = psi16; g0.u16 = u16; g0.rowsqP = rowsqP; g0.cost = cost;
    GemmArgs g1 = {}; // GEMM2: kernel + RK4 bookkeeping
    g1.A = u16; g1.B = u16; g1.lda = D_PAD; g1.ldb = D_PAD; g1.K = D_PAD; g1.gx = 16;
    g1.zcur = z_cur; g1.accb16 = accb16; g1.rowsqP = rowsqP;
    GemmArgs g2 = {}; // final cost quadratic form (t_9)
    g2.A = z16; g2.B = c16T_all + (size_t)18 * CST;
    g2.lda = S_ANCH; g2.ldb = S_ANCH; g2.K = S_ANCH; g2.gx = 22;
    g2.cfp = cfp_all + (size_t)8 * SD; g2.cost = cost;

    int cur_j = -1;
    for (int i = 0; i < 9; i++) {
        float h = ts[i + 1] - ts[i];
        int js[4] = {2 * i, 2 * i + 1, 2 * i + 1, 2 * i + 2};
        float alphas[3] = {0.5f * h, 0.5f * h, h};
        for (int e = 0; e < 4; e++) {
            int j = js[e];
            if (j != cur_j) {
                W10 w;
                for (int f = 0; f < F_NUM; f++) w.w[f] = Wall.w[j][f];
                conv_psi_kernel<<<conv_blocks, 256, 0, stream>>>(data, inputs, conv_w, conv_b, psi16, w);
                cur_j = j;
            }
            g0.A = (e == 0) ? z16 : zt16;
            g0.B = c16T_all + (size_t)j * CST;
            g0.do_cost = (e == 0 && i >= 1) ? 1 : 0;
            g0.cfp = (i >= 1) ? (cfp_all + (size_t)(i - 1) * SD) : cfp_all;
            mfma_gemm<0><<<22 * 48, 256, 0, stream>>>(g0);
            g1.first = (e == 0); g1.finish = (e == 3);
            g1.alpha = (e < 3) ? alphas[e] : 0.f;
            g1.h6 = h / 6.0f; g1.tout = i + 1;
            g1.zt16 = (e < 3) ? zt16 : z16;
            g1.outp = out;
            mfma_gemm<1><<<16 * 48, 256, 0, stream>>>(g1);
        }
    }
    // cost contribution at t_9 (z16 holds z_{t9})
    mfma_gemm<2><<<22 * 16, 256, 0, stream>>>(g2);

    final_kernel<<<1, 256, 0, stream>>>(conv_w, conv_b, cost, out + OUT_Z);
}

// Round 7
// 2755.802 us; speedup vs baseline: 5.2373x; 1.0159x over previous
//
#include <hip/hip_runtime.h>
#include <math.h>

#define S_ANCH 1024
#define B_QRY  2048
#define N_TOT  3072
#define D_DIM  1352
#define D_PAD  1408   // padded D: u16 stride, GEMM2 K, c16T rows (22*64)
#define F_NUM  10
#define N_TV   19
#define NPART  44     // 22 n-tiles * 2 wave-halves in GEMM1

static const size_t SD    = (size_t)S_ANCH * D_DIM;
static const size_t NS    = (size_t)N_TOT * S_ANCH;
static const size_t CST   = (size_t)D_PAD * S_ANCH;   // one c16T plane
static const size_t PSIP  = (size_t)N_TOT * D_PAD;    // one psi plane
static const size_t OUT_Z = (size_t)B_QRY * F_NUM * S_ANCH;

typedef __attribute__((ext_vector_type(8))) short bf16x8;
typedef __attribute__((ext_vector_type(4))) float f32x4;

struct W10  { float w[F_NUM]; };
struct W190 { float w[N_TV][F_NUM]; };

__device__ inline unsigned short f2bf(float x) {
    unsigned int u = __builtin_bit_cast(unsigned int, x);
    unsigned int r = (u + 0x7FFFu + ((u >> 16) & 1u)) >> 16;
    return (unsigned short)r;
}
__device__ inline float bf2f(unsigned short v) {
    unsigned int u = ((unsigned int)v) << 16;
    return __builtin_bit_cast(float, u);
}

__device__ __forceinline__ void stage16(const unsigned short* gp, unsigned short* lp) {
    __builtin_amdgcn_global_load_lds(
        (const __attribute__((address_space(1))) unsigned int*)(const void*)gp,
        (__attribute__((address_space(3))) unsigned int*)(void*)lp, 16, 0, 0);
}

// ---------------- init: zero z, z16, cost, t=0 out slice ----------------
__global__ __launch_bounds__(256) void init_kernel(float* __restrict__ z,
                                                   unsigned short* __restrict__ z16,
                                                   float* __restrict__ cost,
                                                   float* __restrict__ out) {
    size_t idx = (size_t)blockIdx.x * blockDim.x + threadIdx.x;
    size_t stride = (size_t)gridDim.x * blockDim.x;
    for (size_t i = idx; i < NS; i += stride) { z[i] = 0.f; z16[i] = 0; }
    const size_t NO = (size_t)B_QRY * S_ANCH;
    for (size_t i = idx; i < NO; i += stride) {
        size_t b = i >> 10, s = i & 1023;
        out[b * (size_t)(F_NUM * S_ANCH) + s] = 0.f;
    }
    if (idx == 0) cost[0] = 0.f;
}

// ---------------- ALL c_t planes in one pass over c_s ----------------
__global__ __launch_bounds__(256) void c_all_kernel(const float* __restrict__ cs,
                                                    unsigned short* __restrict__ cT,
                                                    float* __restrict__ cfp, W190 W) {
    __shared__ float tile[32][65];
    int d0 = blockIdx.x * 64, s0 = blockIdx.y * 32;
    int t = threadIdx.x;
    int d_l = t & 63, s_base = t >> 6;
    int d = d0 + d_l;
    bool dok = (d < D_DIM);
    float creg[8][F_NUM];
#pragma unroll
    for (int it = 0; it < 8; it++) {
        int s = s0 + s_base + it * 4;
        const float* p = cs + ((size_t)s * D_DIM + d) * F_NUM;
#pragma unroll
        for (int f = 0; f < F_NUM; f++) creg[it][f] = dok ? p[f] : 0.f;
    }
    for (int j = 0; j < N_TV; j++) {
        float v[8];
#pragma unroll
        for (int it = 0; it < 8; it++) {
            float s = 0.f;
#pragma unroll
            for (int f = 0; f < F_NUM; f++) s += creg[it][f] * W.w[j][f];
            v[it] = s;
            tile[s_base + it * 4][d_l] = s;
        }
        if ((j & 1) == 0 && j >= 2 && dok) {
            int gi = (j >> 1) - 1;
#pragma unroll
            for (int it = 0; it < 8; it++)
                cfp[(size_t)gi * SD + (size_t)(s0 + s_base + it * 4) * D_DIM + d] = v[it];
        }
        __syncthreads();
        int s_l = t & 31, dr = t >> 5;
#pragma unroll
        for (int p8 = 0; p8 < 8; p8++) {
            int dd = dr + p8 * 8;
            cT[(size_t)j * CST + (size_t)(d0 + dd) * S_ANCH + s0 + s_l] = f2bf(tile[s_l][dd]);
        }
        __syncthreads();
    }
}

// ---------------- ALL psi_t planes: conv once, 19 freq-dots ----------------
__global__ __launch_bounds__(256) void conv_psi_all_kernel(const float* __restrict__ data,
                                                           const float* __restrict__ inputs,
                                                           const float* __restrict__ cw,
                                                           const float* __restrict__ cb,
                                                           unsigned short* __restrict__ psi_all,
                                                           W190 W) {
    __shared__ float wsh[720];
    __shared__ float bsh[80];
    for (int i = threadIdx.x; i < 720; i += 256) wsh[i] = cw[i];
    for (int i = threadIdx.x; i < 80; i += 256) bsh[i] = cb[i];
    __syncthreads();
    size_t idx = (size_t)blockIdx.x * 256 + threadIdx.x;
    if (idx >= (size_t)N_TOT * 8 * 169) return;
    int pos = (int)(idx % 169);
    int rest = (int)(idx / 169);
    int c8 = rest & 7;
    int n = rest >> 3;
    int oi = pos / 13, oj = pos % 13;
    const float* x = (n < S_ANCH) ? (data + (size_t)n * 784)
                                  : (inputs + (size_t)(n - S_ANCH) * 784);
    float vin[9];
#pragma unroll
    for (int kh = 0; kh < 3; kh++)
#pragma unroll
        for (int kw = 0; kw < 3; kw++)
            vin[kh * 3 + kw] = x[(2 * oi + kh) * 28 + (2 * oj + kw)];
    float s[F_NUM];
#pragma unroll
    for (int f = 0; f < F_NUM; f++) {
        int co = f * 8 + c8;
        float acc = bsh[co];
#pragma unroll
        for (int t = 0; t < 9; t++) acc += vin[t] * wsh[co * 9 + t];
        s[f] = acc;
    }
    size_t base = (size_t)n * D_PAD + c8 * 169 + pos;
#pragma unroll
    for (int j = 0; j < N_TV; j++) {
        float p = 0.f;
#pragma unroll
        for (int f = 0; f < F_NUM; f++) p += s[f] * W.w[j][f];
        psi_all[(size_t)j * PSIP + base] = f2bf(p);
    }
}

// ---------------- MFMA GEMM (NT), 64x64 tile, BK=32, 4-buf 3-deep pipeline ----------------
struct GemmArgs {
    const unsigned short* A; const unsigned short* B;
    int lda, ldb, K, gx;
    // MODE 0
    const unsigned short* psi16; unsigned short* u16; float* rowsqP;
    int do_cost;
    // MODE 0 (cost fusion) + MODE 2
    const float* cfp; float* cost;
    // MODE 1
    float* zcur; unsigned short* accb16; unsigned short* zt16; float* outp;
    int first, finish, tout; float alpha, h6;
};

template<int MODE>
__global__ __launch_bounds__(256) void mfma_gemm(GemmArgs g) {
    __shared__ __align__(16) unsigned short As[4][64][32];
    __shared__ __align__(16) unsigned short Bs[4][64][32];
    __shared__ float sclM[64], ahM[64], sclN[64], ahN[64];
    __shared__ float red4[4];
    // XCD-aware swizzle (all grids are multiples of 8)
    const int nb = gridDim.x;
    const int lin = blockIdx.x;
    const int swz = (lin & 7) * (nb >> 3) + (lin >> 3);
    const int bx = swz % g.gx, by = swz / g.gx;
    const int bm = by * 64, bn = bx * 64;
    const int t = threadIdx.x;
    const int lane = t & 63, wv = t >> 6;
    const int wm = (wv >> 1) * 32, wn = (wv & 1) * 32;
    const int lr = lane & 15, lg = lane >> 4;

    if (MODE == 1) {
        if (t < 128) {
            int r = (t < 64) ? (bm + t) : (bn + (t - 64));
            float tot = 0.f;
#pragma unroll
            for (int c = 0; c < NPART; c++) tot += g.rowsqP[(size_t)c * N_TOT + r];
            float norm = sqrtf(tot + 1e-6f);
            float sg = 1.f / (1.f + __expf(-norm));
            float sc = sg / norm;
            float a = 0.5f * tot * sc * sc;
            if (t < 64) { sclM[t] = sc; ahM[t] = a; }
            else        { sclN[t - 64] = sc; ahN[t - 64] = a; }
        }
    }

    f32x4 acc[2][2];
#pragma unroll
    for (int i = 0; i < 2; i++)
#pragma unroll
        for (int j = 0; j < 2; j++) acc[i][j] = (f32x4){0.f, 0.f, 0.f, 0.f};

    // staging: 1 gload_lds per matrix per thread per K-step; linear LDS dest,
    // inverse-swizzled global source chunk (rule 21: both-sides-or-neither).
    const int srow = lane >> 2;                         // 0..15 within wave's 16 rows
    const int gch  = (lane & 3) ^ ((lane >> 3) & 3);    // source 16B chunk
    const unsigned short* Abase = g.A + (size_t)(bm + wv * 16 + srow) * g.lda + gch * 8;
    const unsigned short* Bbase = g.B + (size_t)(bn + wv * 16 + srow) * g.ldb + gch * 8;

    auto STAGE = [&](int tt) {
        int buf = tt & 3;
        stage16(Abase + (tt << 5), &As[buf][wv * 16][0]);
        stage16(Bbase + (tt << 5), &Bs[buf][wv * 16][0]);
    };
    const int sl = lg ^ ((lr >> 1) & 3);                // swizzled read slot
    auto COMPUTE = [&](int buf) {
        bf16x8 af[2], bf[2];
#pragma unroll
        for (int i = 0; i < 2; i++)
            af[i] = *(const bf16x8*)&As[buf][wm + i * 16 + lr][sl * 8];
#pragma unroll
        for (int j = 0; j < 2; j++)
            bf[j] = *(const bf16x8*)&Bs[buf][wn + j * 16 + lr][sl * 8];
#pragma unroll
        for (int i = 0; i < 2; i++)
#pragma unroll
            for (int j = 0; j < 2; j++)
                acc[i][j] = __builtin_amdgcn_mfma_f32_16x16x32_bf16(af[i], bf[j], acc[i][j], 0, 0, 0);
    };

    const int nt = g.K >> 5;
    STAGE(0); STAGE(1); STAGE(2);
    for (int tt = 0; tt < nt - 2; ++tt) {
        asm volatile("s_waitcnt vmcnt(4)" ::: "memory");
        __builtin_amdgcn_s_barrier();
        __builtin_amdgcn_sched_barrier(0);
        if (tt + 3 < nt) STAGE(tt + 3);
        COMPUTE(tt & 3);
    }
    asm volatile("s_waitcnt vmcnt(2)" ::: "memory");
    __builtin_amdgcn_s_barrier();
    __builtin_amdgcn_sched_barrier(0);
    COMPUTE((nt - 2) & 3);
    asm volatile("s_waitcnt vmcnt(0)" ::: "memory");
    __builtin_amdgcn_s_barrier();
    __builtin_amdgcn_sched_barrier(0);
    COMPUTE((nt - 1) & 3);

    // ---------------- epilogues ----------------
    if (MODE == 0) {
        const bool docost = g.do_cost && (bm < S_ANCH);
        float cst = 0.f;
#pragma unroll
        for (int i = 0; i < 2; i++) {
#pragma unroll
            for (int reg = 0; reg < 4; reg++) {
                int m = bm + wm + i * 16 + lg * 4 + reg;
                float sq = 0.f;
#pragma unroll
                for (int j = 0; j < 2; j++) {
                    int n = bn + wn + j * 16 + lr;
                    float v = acc[i][j][reg];
                    bool nok = n < D_DIM;
                    if (docost && nok) cst += v * g.cfp[(size_t)m * D_DIM + n];
                    if (nok) v += bf2f(g.psi16[(size_t)m * D_PAD + n]);
                    else v = 0.f;
                    g.u16[(size_t)m * D_PAD + n] = f2bf(v);
                    sq += v * v;
                }
                sq += __shfl_xor(sq, 1);
                sq += __shfl_xor(sq, 2);
                sq += __shfl_xor(sq, 4);
                sq += __shfl_xor(sq, 8);
                if (lr == 0)
                    g.rowsqP[(size_t)(bx * 2 + (wn >> 5)) * N_TOT + m] = sq;
            }
        }
        if (docost) {
            cst += __shfl_xor(cst, 1); cst += __shfl_xor(cst, 2);
            cst += __shfl_xor(cst, 4); cst += __shfl_xor(cst, 8);
            cst += __shfl_xor(cst, 16); cst += __shfl_xor(cst, 32);
            if (lane == 0) red4[wv] = cst;
            __syncthreads();
            if (t == 0) atomicAdd(g.cost, red4[0] + red4[1] + red4[2] + red4[3]);
        }
    } else if (MODE == 1) {
        __syncthreads();  // stats visibility
#pragma unroll
        for (int i = 0; i < 2; i++) {
#pragma unroll
            for (int reg = 0; reg < 4; reg++) {
                int mi = wm + i * 16 + lg * 4 + reg;
                int m = bm + mi;
                float sm = sclM[mi], am = ahM[mi];
#pragma unroll
                for (int j = 0; j < 2; j++) {
                    int ni = wn + j * 16 + lr;
                    int n = bn + ni;
                    float uv = acc[i][j][reg] * sm * sclN[ni];
                    float kv = __expf(uv - am - ahN[ni]) * uv;
                    size_t idx = (size_t)m * S_ANCH + n;
                    if (!g.finish) {
                        float ab = g.first ? kv : (bf2f(g.accb16[idx]) + 2.0f * kv);
                        g.accb16[idx] = f2bf(ab);
                        float zt = g.zcur[idx] + g.alpha * kv;
                        g.zt16[idx] = f2bf(zt);
                    } else {
                        float z = g.zcur[idx] + g.h6 * (bf2f(g.accb16[idx]) + kv);
                        g.zcur[idx] = z;
                        g.zt16[idx] = f2bf(z);
                        if (m >= S_ANCH)
                            g.outp[(size_t)(m - S_ANCH) * (F_NUM * S_ANCH)
                                   + (size_t)g.tout * S_ANCH + n] = z;
                    }
                }
            }
        }
    } else {
        float s = 0.f;
#pragma unroll
        for (int i = 0; i < 2; i++)
#pragma unroll
            for (int reg = 0; reg < 4; reg++) {
                int m = bm + wm + i * 16 + lg * 4 + reg;
#pragma unroll
                for (int j = 0; j < 2; j++) {
                    int n = bn + wn + j * 16 + lr;
                    if (n < D_DIM) s += acc[i][j][reg] * g.cfp[(size_t)m * D_DIM + n];
                }
            }
        s += __shfl_xor(s, 1); s += __shfl_xor(s, 2); s += __shfl_xor(s, 4);
        s += __shfl_xor(s, 8); s += __shfl_xor(s, 16); s += __shfl_xor(s, 32);
        if (lane == 0) red4[wv] = s;
        __syncthreads();
        if (t == 0) atomicAdd(g.cost, red4[0] + red4[1] + red4[2] + red4[3]);
    }
}

// ---------------- final: add conv_w/b square norm ----------------
__global__ __launch_bounds__(256) void final_kernel(const float* __restrict__ cw,
                                                    const float* __restrict__ cb,
                                                    const float* __restrict__ cost,
                                                    float* __restrict__ out) {
    float s = 0.f;
    for (int i = threadIdx.x; i < 720; i += 256) s += cw[i] * cw[i];
    for (int i = threadIdx.x; i < 80; i += 256) s += cb[i] * cb[i];
    for (int o = 32; o > 0; o >>= 1) s += __shfl_down(s, o);
    __shared__ float red[4];
    if ((threadIdx.x & 63) == 0) red[threadIdx.x >> 6] = s;
    __syncthreads();
    if (threadIdx.x == 0) out[0] = red[0] + red[1] + red[2] + red[3] + cost[0] / 10.0f;
}

// ---------------- host ----------------
extern "C" void kernel_launch(void* const* d_in, const int* in_sizes, int n_in,
                              void* d_out, int out_size, void* d_ws, size_t ws_size,
                              hipStream_t stream) {
    (void)in_sizes; (void)n_in; (void)out_size; (void)ws_size;
    const float* data   = (const float*)d_in[0];
    const float* inputs = (const float*)d_in[1];
    const float* conv_w = (const float*)d_in[2];
    const float* conv_b = (const float*)d_in[3];
    const float* c_s    = (const float*)d_in[4];
    float* out = (float*)d_out;

    char* ws = (char*)d_ws;
    size_t off = 0;
    auto alloc = [&](size_t bytes) {
        char* p = ws + off; off += (bytes + 255) & ~(size_t)255; return p;
    };
    unsigned short* c16T_all = (unsigned short*)alloc((size_t)N_TV * CST * 2);   // 54.8 MB
    float*          cfp_all  = (float*)alloc((size_t)9 * SD * 4);                // 49.8 MB
    unsigned short* psi_all  = (unsigned short*)alloc((size_t)N_TV * PSIP * 2);  // 164.4 MB
    unsigned short* u16      = (unsigned short*)alloc(PSIP * 2);
    float*          z_cur    = (float*)alloc(NS * 4);
    unsigned short* z16      = (unsigned short*)alloc(NS * 2);
    unsigned short* zt16     = (unsigned short*)alloc(NS * 2);
    unsigned short* accb16   = (unsigned short*)alloc(NS * 2);
    float*          rowsqP   = (float*)alloc((size_t)NPART * N_TOT * 4);
    float*          cost     = (float*)alloc(64);

    const double TAU_D = 6.2831853071795864769;
    float ts[F_NUM];
    for (int i = 0; i < F_NUM; i++) ts[i] = (float)((double)i / 9.0);
    W190 Wall;
    for (int j = 0; j < N_TV; j++) {
        float tt;
        if ((j & 1) == 0) tt = ts[j >> 1];
        else {
            int i = j >> 1;
            float h = ts[i + 1] - ts[i];
            tt = ts[i] + 0.5f * h;
        }
        for (int f = 0; f < F_NUM; f++) {
            float coeff = (float)(TAU_D * f);
            float targ = tt * coeff;
            Wall.w[j][f] = (float)cos((double)targ);
        }
    }

    init_kernel<<<2048, 256, 0, stream>>>(z_cur, z16, cost, out);
    c_all_kernel<<<dim3(22, 32), 256, 0, stream>>>(c_s, c16T_all, cfp_all, Wall);
    const int conv_blocks = (int)(((size_t)N_TOT * 8 * 169 + 255) / 256);
    conv_psi_all_kernel<<<conv_blocks, 256, 0, stream>>>(data, inputs, conv_w, conv_b,
                                                         psi_all, Wall);

    GemmArgs g0 = {}; // GEMM1: u = z@cT + psi (+ fused cost at e=0)
    g0.lda = S_ANCH; g0.ldb = S_ANCH; g0.K = S_ANCH; g0.gx = 22;
    g0.u16 = u16; g0.rowsqP = rowsqP; g0.cost = cost;
    GemmArgs g1 = {}; // GEMM2: kernel + RK4 bookkeeping
    g1.A = u16; g1.B = u16; g1.lda = D_PAD; g1.ldb = D_PAD; g1.K = D_PAD; g1.gx = 16;
    g1.zcur = z_cur; g1.accb16 = accb16; g1.rowsqP = rowsqP;
    GemmArgs g2 = {}; // final cost quadratic form (t_9)
    g2.A = z16; g2.B = c16T_all + (size_t)18 * CST;
    g2.lda = S_ANCH; g2.ldb = S_ANCH; g2.K = S_ANCH; g2.gx = 22;
    g2.cfp = cfp_all + (size_t)8 * SD; g2.cost = cost;

    for (int i = 0; i < 9; i++) {
        float h = ts[i + 1] - ts[i];
        int js[4] = {2 * i, 2 * i + 1, 2 * i + 1, 2 * i + 2};
        float alphas[3] = {0.5f * h, 0.5f * h, h};
        for (int e = 0; e < 4; e++) {
            int j = js[e];
            g0.A = (e == 0) ? z16 : zt16;
            g0.B = c16T_all + (size_t)j * CST;
            g0.psi16 = psi_all + (size_t)j * PSIP;
            g0.do_cost = (e == 0 && i >= 1) ? 1 : 0;
            g0.cfp = (i >= 1) ? (cfp_all + (size_t)(i - 1) * SD) : cfp_all;
            mfma_gemm<0><<<22 * 48, 256, 0, stream>>>(g0);
            g1.first = (e == 0); g1.finish = (e == 3);
            g1.alpha = (e < 3) ? alphas[e] : 0.f;
            g1.h6 = h / 6.0f; g1.tout = i + 1;
            g1.zt16 = (e < 3) ? zt16 : z16;
            g1.outp = out;
            mfma_gemm<1><<<16 * 48, 256, 0, stream>>>(g1);
        }
    }
    // cost contribution at t_9 (z16 holds z_{t9})
    mfma_gemm<2><<<22 * 16, 256, 0, stream>>>(g2);

    final_kernel<<<1, 256, 0, stream>>>(conv_w, conv_b, cost, out + OUT_Z);
}